// Round 5
// baseline (349.245 us; speedup 1.0000x reference)
//
#include <hip/hip_runtime.h>
#include <hip/hip_bf16.h>

#define IN_FEAT 4096
#define OUT_FEAT 4096
#define FP_FEAT 256
#define INT_FEAT 3840
#define TOKENS 4096
#define PACKED_W (INT_FEAT / 2)  // 1920

typedef __attribute__((ext_vector_type(8))) short short8;
typedef __attribute__((ext_vector_type(4))) float f32x4;

// ---------------------------------------------------------------- quantize ---
// One block per token row. x is f32 on device (fp16 ref -> f32, proven r1/r2).
// Index storage (i32 vs i64 words) sniffed deterministically; resolved i32.
__global__ __launch_bounds__(256) void quant_kernel(
    const float* __restrict__ x,
    const int* __restrict__ int_idx_raw,
    const int* __restrict__ fp_idx_raw,
    __hip_bfloat16* __restrict__ Aq,
    float* __restrict__ scale_ws,
    float* __restrict__ zero_ws)
{
    const int m = blockIdx.x;
    const int t = threadIdx.x;
    const float* xr = x + (size_t)m * IN_FEAT;

    const bool is64 = (int_idx_raw[1] == 0) && (int_idx_raw[3] == 0);

    float v[15];
    float mn = 1e30f, mx = -1e30f;
#pragma unroll
    for (int j = 0; j < 15; ++j) {
        int k = t + j * 256;
        int idx = is64 ? int_idx_raw[2 * k] : int_idx_raw[k];
        float f = xr[idx];
        v[j] = f;
        mn = fminf(mn, f);
        mx = fmaxf(mx, f);
    }
#pragma unroll
    for (int off = 1; off < 64; off <<= 1) {
        mn = fminf(mn, __shfl_xor(mn, off));
        mx = fmaxf(mx, __shfl_xor(mx, off));
    }
    __shared__ float smn[4], smx[4];
    int wid = t >> 6, lane = t & 63;
    if (lane == 0) { smn[wid] = mn; smx[wid] = mx; }
    __syncthreads();
    if (t == 0) {
        float rmn = fminf(fminf(smn[0], smn[1]), fminf(smn[2], smn[3]));
        float rmx = fmaxf(fmaxf(smx[0], smx[1]), fmaxf(smx[2], smx[3]));
        float sc = fmaxf((rmx - rmn) / 15.0f, 1e-8f);
        smn[0] = rmn;
        smx[0] = sc;
        scale_ws[m] = sc;
        zero_ws[m] = rmn;
    }
    __syncthreads();
    const float zero = smn[0];
    const float sc = smx[0];

    __hip_bfloat16* ar = Aq + (size_t)m * IN_FEAT;
#pragma unroll
    for (int j = 0; j < 15; ++j) {
        int k = t + j * 256;
        float q = rintf((v[j] - zero) / sc) - 8.0f;   // f32 IEEE div + rndne == np
        q = fminf(fmaxf(q, -8.0f), 7.0f);
        ar[k] = __float2bfloat16(q);                  // exact small int
    }
    int fpi = is64 ? fp_idx_raw[2 * t] : fp_idx_raw[t];
    ar[INT_FEAT + t] = __float2bfloat16(xr[fpi]);
}

// ------------------------------------------------------------ weight unpack --
__global__ __launch_bounds__(256) void unpack_kernel(
    const int* __restrict__ wpacked_raw,       // u8 ref; storage sniffed (i32)
    const float* __restrict__ fpw,             // [OUT][256] f32
    __hip_bfloat16* __restrict__ Wb)           // [OUT][4096]
{
    const int n = blockIdx.x, t = threadIdx.x;

    bool is_i32 = true;
#pragma unroll
    for (int j = 0; j < 8; ++j) {
        unsigned w = (unsigned)wpacked_raw[j];
        if (w > 0xFFu) is_i32 = false;
    }

    __hip_bfloat16* wo = Wb + (size_t)n * IN_FEAT;
    if (is_i32) {
        const int* wr = wpacked_raw + (size_t)n * PACKED_W;
#pragma unroll
        for (int j = 0; j < 8; ++j) {
            int k = t + j * 256;
            if (k < PACKED_W) {
                int p = wr[k];
                int lo = p & 15; if (lo >= 8) lo -= 16;
                int hi = (p >> 4) & 15; if (hi >= 8) hi -= 16;
                wo[2 * k]     = __float2bfloat16((float)lo);
                wo[2 * k + 1] = __float2bfloat16((float)hi);
            }
        }
    } else {
        const unsigned char* wr = (const unsigned char*)wpacked_raw
                                  + (size_t)n * PACKED_W;
#pragma unroll
        for (int j = 0; j < 8; ++j) {
            int k = t + j * 256;
            if (k < PACKED_W) {
                int p = wr[k];
                int lo = p & 15; if (lo >= 8) lo -= 16;
                int hi = (p >> 4) & 15; if (hi >= 8) hi -= 16;
                wo[2 * k]     = __float2bfloat16((float)lo);
                wo[2 * k + 1] = __float2bfloat16((float)hi);
            }
        }
    }
    wo[INT_FEAT + t] = __float2bfloat16(fpw[(size_t)n * FP_FEAT + t]);
}

// ------------------------------------------------------------------- GEMM ----
// 128x128 tile, BK=64, 4 waves (2x2), mfma_f32_16x16x32_bf16, global_load_lds
// staging. Two accumulator sets: int part (k-tiles 0..59, bit-exact: products
// <=64, |acc| <= 245760 < 2^24) and fp part (60..63). Output is FLOAT32.

__device__ __forceinline__ void stage_tile(
    const __hip_bfloat16* gA, const __hip_bfloat16* gB, int k0,
    __hip_bfloat16* ldsA, __hip_bfloat16* ldsB, int t)
{
#pragma unroll
    for (int i = 0; i < 4; ++i) {
        __builtin_amdgcn_global_load_lds(
            (const __attribute__((address_space(1))) void*)(gA + (size_t)i * 32 * IN_FEAT + k0),
            (__attribute__((address_space(3))) void*)&ldsA[i * 2048 + t * 8], 16, 0, 0);
        __builtin_amdgcn_global_load_lds(
            (const __attribute__((address_space(1))) void*)(gB + (size_t)i * 32 * IN_FEAT + k0),
            (__attribute__((address_space(3))) void*)&ldsB[i * 2048 + t * 8], 16, 0, 0);
    }
}

__device__ __forceinline__ void compute_tile(
    const __hip_bfloat16* __restrict__ ldsA,
    const __hip_bfloat16* __restrict__ ldsB,
    int lane, int wr, int wc, f32x4 (&acc)[4][4])
{
    const int rsel = lane & 15;
    const int koct = (lane >> 4) * 8;
#pragma unroll
    for (int ks = 0; ks < 2; ++ks) {
        short8 af[4], bfr[4];
#pragma unroll
        for (int mf = 0; mf < 4; ++mf)
            af[mf] = *(const short8*)&ldsA[(wr * 64 + mf * 16 + rsel) * 64 + ks * 32 + koct];
#pragma unroll
        for (int nf = 0; nf < 4; ++nf)
            bfr[nf] = *(const short8*)&ldsB[(wc * 64 + nf * 16 + rsel) * 64 + ks * 32 + koct];
#pragma unroll
        for (int mf = 0; mf < 4; ++mf)
#pragma unroll
            for (int nf = 0; nf < 4; ++nf)
                acc[mf][nf] = __builtin_amdgcn_mfma_f32_16x16x32_bf16(
                    af[mf], bfr[nf], acc[mf][nf], 0, 0, 0);
    }
}

__global__ __launch_bounds__(256) void gemm_kernel(
    const __hip_bfloat16* __restrict__ Aq,     // [TOKENS][4096]
    const __hip_bfloat16* __restrict__ Wb,     // [OUT][4096]
    const float* __restrict__ scale_ws,
    const float* __restrict__ zero_ws,
    const float* __restrict__ wscale,
    const float* __restrict__ reduced,
    const float* __restrict__ bias,
    float* __restrict__ out)                   // f32 output (fp16 ref -> f32)
{
    __shared__ __hip_bfloat16 ldsA[128 * 64];
    __shared__ __hip_bfloat16 ldsB[128 * 64];

    const int t = threadIdx.x;
    const int lane = t & 63, wid = t >> 6;
    const int wr = wid >> 1, wc = wid & 1;
    const int tileM = blockIdx.x * 128, tileN = blockIdx.y * 128;

    f32x4 accI[4][4] = {{{0.f}}};
    f32x4 accF[4][4] = {{{0.f}}};

    const int srow = t >> 3;
    const int scol = (t & 7) * 8;
    const __hip_bfloat16* gA = Aq + (size_t)(tileM + srow) * IN_FEAT + scol;
    const __hip_bfloat16* gB = Wb + (size_t)(tileN + srow) * IN_FEAT + scol;

    for (int kt = 0; kt < 60; ++kt) {          // int columns, K 0..3839
        stage_tile(gA, gB, kt * 64, ldsA, ldsB, t);
        __syncthreads();
        compute_tile(ldsA, ldsB, lane, wr, wc, accI);
        __syncthreads();
    }
    for (int kt = 60; kt < 64; ++kt) {         // fp columns, K 3840..4095
        stage_tile(gA, gB, kt * 64, ldsA, ldsB, t);
        __syncthreads();
        compute_tile(ldsA, ldsB, lane, wr, wc, accF);
        __syncthreads();
    }

    // epilogue: out = s*ws*accI + (z + 8s)*red + accF + bias  (np op order)
    const int cn = lane & 15;
    const int cr4 = (lane >> 4) * 4;
#pragma unroll
    for (int mf = 0; mf < 4; ++mf) {
#pragma unroll
        for (int nf = 0; nf < 4; ++nf) {
            int n = tileN + wc * 64 + nf * 16 + cn;
            float ws = wscale[n];
            float rd = reduced[n];
            float bs = bias[n];
#pragma unroll
            for (int i = 0; i < 4; ++i) {
                int m = tileM + wr * 64 + mf * 16 + cr4 + i;
                float sc = scale_ws[m];
                float zr = zero_ws[m];
                out[(size_t)m * OUT_FEAT + n] =
                    sc * ws * accI[mf][nf][i]
                    + (zr + sc * 8.0f) * rd
                    + accF[mf][nf][i] + bs;
            }
        }
    }
}

// ------------------------------------------------------------------ launch ---
extern "C" void kernel_launch(void* const* d_in, const int* in_sizes, int n_in,
                              void* d_out, int out_size, void* d_ws, size_t ws_size,
                              hipStream_t stream)
{
    // Robust input remap by flat element count (unique sizes pin the buffers;
    // the three 4096-element inputs keep dict order: wscale, reduced, bias).
    const void* px = 0; const void* pw = 0; const void* pfpw = 0;
    const void* pii = 0; const void* pfi = 0;
    const void* p4096[3] = {0, 0, 0}; int n4096 = 0;
    for (int i = 0; i < n_in; ++i) {
        switch (in_sizes[i]) {
            case 16777216: px = d_in[i]; break;           // x (1,4096,4096)
            case 7864320:  pw = d_in[i]; break;           // int_weight (4096,1920)
            case 1048576:  pfpw = d_in[i]; break;         // fp_weight (4096,256)
            case 3840:     pii = d_in[i]; break;          // int_indices
            case 256:      pfi = d_in[i]; break;          // fp_indices
            case 4096:     if (n4096 < 3) p4096[n4096++] = d_in[i]; break;
            default: break;
        }
    }
    if (!px || !pw || !pfpw || !pii || !pfi || n4096 != 3) return;

    const float* x       = (const float*)px;
    const int*   wpacked = (const int*)pw;
    const float* wscale  = (const float*)p4096[0];
    const float* reduced = (const float*)p4096[1];
    const float* bias    = (const float*)p4096[2];
    const float* fpw     = (const float*)pfpw;
    const int*   int_idx = (const int*)pii;
    const int*   fp_idx  = (const int*)pfi;
    float*       out     = (float*)d_out;      // f32 (fp16 ref output -> float*)

    const size_t NEED = (size_t)67108864 + 32768;
    if (ws_size < NEED) return;

    char* ws = (char*)d_ws;
    __hip_bfloat16* Aq = (__hip_bfloat16*)ws;                            // 32 MiB
    __hip_bfloat16* Wb = (__hip_bfloat16*)(ws + (size_t)33554432);       // 32 MiB
    float* scale_ws    = (float*)(ws + (size_t)67108864);                // 16 KiB
    float* zero_ws     = (float*)(ws + (size_t)67108864 + 16384);        // 16 KiB

    quant_kernel<<<TOKENS, 256, 0, stream>>>(x, int_idx, fp_idx, Aq, scale_ws, zero_ws);
    unpack_kernel<<<OUT_FEAT, 256, 0, stream>>>(wpacked, fpw, Wb);
    dim3 grid(TOKENS / 128, OUT_FEAT / 128);
    gemm_kernel<<<grid, 256, 0, stream>>>(Aq, Wb, scale_ws, zero_ws,
                                          wscale, reduced, bias, out);
}

// Round 6
// 221.374 us; speedup vs baseline: 1.5776x; 1.5776x over previous
//
#include <hip/hip_runtime.h>
#include <hip/hip_bf16.h>

#define IN_FEAT 4096
#define OUT_FEAT 4096
#define FP_FEAT 256
#define INT_FEAT 3840
#define TOKENS 4096
#define PACKED_W (INT_FEAT / 2)  // 1920

typedef __attribute__((ext_vector_type(8))) short short8;
typedef __attribute__((ext_vector_type(4))) float f32x4;

// ---------------------------------------------------------------- quantize ---
// One block per token row. x is f32 on device. Writes q (exact) to int cols,
// and x_fp / sc_m to fp cols (fold: fp part shares the int accumulator and is
// re-scaled by sc*ws in the epilogue).
__global__ __launch_bounds__(256) void quant_kernel(
    const float* __restrict__ x,
    const int* __restrict__ int_idx_raw,
    const int* __restrict__ fp_idx_raw,
    __hip_bfloat16* __restrict__ Aq,
    float* __restrict__ scale_ws,
    float* __restrict__ zero_ws)
{
    const int m = blockIdx.x;
    const int t = threadIdx.x;
    const float* xr = x + (size_t)m * IN_FEAT;

    const bool is64 = (int_idx_raw[1] == 0) && (int_idx_raw[3] == 0);

    float v[15];
    float mn = 1e30f, mx = -1e30f;
#pragma unroll
    for (int j = 0; j < 15; ++j) {
        int k = t + j * 256;
        int idx = is64 ? int_idx_raw[2 * k] : int_idx_raw[k];
        float f = xr[idx];
        v[j] = f;
        mn = fminf(mn, f);
        mx = fmaxf(mx, f);
    }
#pragma unroll
    for (int off = 1; off < 64; off <<= 1) {
        mn = fminf(mn, __shfl_xor(mn, off));
        mx = fmaxf(mx, __shfl_xor(mx, off));
    }
    __shared__ float smn[4], smx[4];
    int wid = t >> 6, lane = t & 63;
    if (lane == 0) { smn[wid] = mn; smx[wid] = mx; }
    __syncthreads();
    if (t == 0) {
        float rmn = fminf(fminf(smn[0], smn[1]), fminf(smn[2], smn[3]));
        float rmx = fmaxf(fmaxf(smx[0], smx[1]), fmaxf(smx[2], smx[3]));
        float sc = fmaxf((rmx - rmn) / 15.0f, 1e-8f);
        smn[0] = rmn;
        smx[0] = sc;
        scale_ws[m] = sc;
        zero_ws[m] = rmn;
    }
    __syncthreads();
    const float zero = smn[0];
    const float sc = smx[0];

    __hip_bfloat16* ar = Aq + (size_t)m * IN_FEAT;
#pragma unroll
    for (int j = 0; j < 15; ++j) {
        int k = t + j * 256;
        float q = rintf((v[j] - zero) / sc) - 8.0f;   // f32 IEEE div + rndne == np
        q = fminf(fmaxf(q, -8.0f), 7.0f);
        ar[k] = __float2bfloat16(q);                  // exact small int
    }
    int fpi = is64 ? fp_idx_raw[2 * t] : fp_idx_raw[t];
    ar[INT_FEAT + t] = __float2bfloat16(xr[fpi] / sc);   // fp col pre-divided
}

// ------------------------------------------------------------ weight unpack --
// fp cols stored as w_fp / ws_n (fold into shared accumulator).
__global__ __launch_bounds__(256) void unpack_kernel(
    const int* __restrict__ wpacked_raw,       // u8 ref; storage sniffed (i32)
    const float* __restrict__ fpw,             // [OUT][256] f32
    const float* __restrict__ wscale,          // [OUT]
    __hip_bfloat16* __restrict__ Wb)           // [OUT][4096]
{
    const int n = blockIdx.x, t = threadIdx.x;

    bool is_i32 = true;
#pragma unroll
    for (int j = 0; j < 8; ++j) {
        unsigned w = (unsigned)wpacked_raw[j];
        if (w > 0xFFu) is_i32 = false;
    }

    __hip_bfloat16* wo = Wb + (size_t)n * IN_FEAT;
    if (is_i32) {
        const int* wr = wpacked_raw + (size_t)n * PACKED_W;
#pragma unroll
        for (int j = 0; j < 8; ++j) {
            int k = t + j * 256;
            if (k < PACKED_W) {
                int p = wr[k];
                int lo = p & 15; if (lo >= 8) lo -= 16;
                int hi = (p >> 4) & 15; if (hi >= 8) hi -= 16;
                wo[2 * k]     = __float2bfloat16((float)lo);
                wo[2 * k + 1] = __float2bfloat16((float)hi);
            }
        }
    } else {
        const unsigned char* wr = (const unsigned char*)wpacked_raw
                                  + (size_t)n * PACKED_W;
#pragma unroll
        for (int j = 0; j < 8; ++j) {
            int k = t + j * 256;
            if (k < PACKED_W) {
                int p = wr[k];
                int lo = p & 15; if (lo >= 8) lo -= 16;
                int hi = (p >> 4) & 15; if (hi >= 8) hi -= 16;
                wo[2 * k]     = __float2bfloat16((float)lo);
                wo[2 * k + 1] = __float2bfloat16((float)hi);
            }
        }
    }
    float wsn = wscale[n];
    wo[INT_FEAT + t] = __float2bfloat16(fpw[(size_t)n * FP_FEAT + t] / wsn);
}

// ------------------------------------------------------------------- GEMM ----
// 128x128 tile, BK=64, 4 waves (2x2), mfma_f32_16x16x32_bf16, global_load_lds
// staging. SINGLE accumulator over full K=4096 (fp cols pre-scaled by
// 1/sc_m and 1/ws_n). Int partial sums bit-exact; fp adds are ~1e-4 rounding
// on an O(1e3) acc, scaled by sc*ws ~ 2e-3 in the epilogue -> negligible.
__device__ __forceinline__ void stage_tile(
    const __hip_bfloat16* gA, const __hip_bfloat16* gB, int k0,
    __hip_bfloat16* ldsA, __hip_bfloat16* ldsB, int t)
{
#pragma unroll
    for (int i = 0; i < 4; ++i) {
        __builtin_amdgcn_global_load_lds(
            (const __attribute__((address_space(1))) void*)(gA + (size_t)i * 32 * IN_FEAT + k0),
            (__attribute__((address_space(3))) void*)&ldsA[i * 2048 + t * 8], 16, 0, 0);
        __builtin_amdgcn_global_load_lds(
            (const __attribute__((address_space(1))) void*)(gB + (size_t)i * 32 * IN_FEAT + k0),
            (__attribute__((address_space(3))) void*)&ldsB[i * 2048 + t * 8], 16, 0, 0);
    }
}

__device__ __forceinline__ void compute_tile(
    const __hip_bfloat16* __restrict__ ldsA,
    const __hip_bfloat16* __restrict__ ldsB,
    int lane, int wr, int wc, f32x4 (&acc)[4][4])
{
    const int rsel = lane & 15;
    const int koct = (lane >> 4) * 8;
#pragma unroll
    for (int ks = 0; ks < 2; ++ks) {
        short8 af[4], bfr[4];
#pragma unroll
        for (int mf = 0; mf < 4; ++mf)
            af[mf] = *(const short8*)&ldsA[(wr * 64 + mf * 16 + rsel) * 64 + ks * 32 + koct];
#pragma unroll
        for (int nf = 0; nf < 4; ++nf)
            bfr[nf] = *(const short8*)&ldsB[(wc * 64 + nf * 16 + rsel) * 64 + ks * 32 + koct];
#pragma unroll
        for (int mf = 0; mf < 4; ++mf)
#pragma unroll
            for (int nf = 0; nf < 4; ++nf)
                acc[mf][nf] = __builtin_amdgcn_mfma_f32_16x16x32_bf16(
                    af[mf], bfr[nf], acc[mf][nf], 0, 0, 0);
    }
}

__global__ __launch_bounds__(256) void gemm_kernel(
    const __hip_bfloat16* __restrict__ Aq,     // [TOKENS][4096]
    const __hip_bfloat16* __restrict__ Wb,     // [OUT][4096]
    const float* __restrict__ scale_ws,
    const float* __restrict__ zero_ws,
    const float* __restrict__ wscale,
    const float* __restrict__ reduced,
    const float* __restrict__ bias,
    float* __restrict__ out)                   // f32 output
{
    __shared__ __hip_bfloat16 ldsA[128 * 64];
    __shared__ __hip_bfloat16 ldsB[128 * 64];

    const int t = threadIdx.x;
    const int lane = t & 63, wid = t >> 6;
    const int wr = wid >> 1, wc = wid & 1;
    const int tileM = blockIdx.x * 128, tileN = blockIdx.y * 128;

    f32x4 acc[4][4] = {{{0.f}}};

    const int srow = t >> 3;
    const int scol = (t & 7) * 8;
    const __hip_bfloat16* gA = Aq + (size_t)(tileM + srow) * IN_FEAT + scol;
    const __hip_bfloat16* gB = Wb + (size_t)(tileN + srow) * IN_FEAT + scol;

    for (int kt = 0; kt < 64; ++kt) {
        stage_tile(gA, gB, kt * 64, ldsA, ldsB, t);
        __syncthreads();
        compute_tile(ldsA, ldsB, lane, wr, wc, acc);
        __syncthreads();
    }

    // epilogue: out = sc*ws*acc + (zero + 8*sc)*reduced + bias
    const int cn = lane & 15;
    const int cr4 = (lane >> 4) * 4;
#pragma unroll
    for (int mf = 0; mf < 4; ++mf) {
#pragma unroll
        for (int nf = 0; nf < 4; ++nf) {
            int n = tileN + wc * 64 + nf * 16 + cn;
            float ws = wscale[n];
            float rd = reduced[n];
            float bs = bias[n];
#pragma unroll
            for (int i = 0; i < 4; ++i) {
                int m = tileM + wr * 64 + mf * 16 + cr4 + i;
                float sc = scale_ws[m];
                float zr = zero_ws[m];
                out[(size_t)m * OUT_FEAT + n] =
                    sc * ws * acc[mf][nf][i]
                    + (zr + sc * 8.0f) * rd + bs;
            }
        }
    }
}

// ------------------------------------------------------------------ launch ---
extern "C" void kernel_launch(void* const* d_in, const int* in_sizes, int n_in,
                              void* d_out, int out_size, void* d_ws, size_t ws_size,
                              hipStream_t stream)
{
    // Input remap by flat element count (unique sizes pin the buffers; the
    // three 4096-element inputs keep dict order: wscale, reduced, bias).
    const void* px = 0; const void* pw = 0; const void* pfpw = 0;
    const void* pii = 0; const void* pfi = 0;
    const void* p4096[3] = {0, 0, 0}; int n4096 = 0;
    for (int i = 0; i < n_in; ++i) {
        switch (in_sizes[i]) {
            case 16777216: px = d_in[i]; break;           // x (1,4096,4096)
            case 7864320:  pw = d_in[i]; break;           // int_weight
            case 1048576:  pfpw = d_in[i]; break;         // fp_weight
            case 3840:     pii = d_in[i]; break;          // int_indices
            case 256:      pfi = d_in[i]; break;          // fp_indices
            case 4096:     if (n4096 < 3) p4096[n4096++] = d_in[i]; break;
            default: break;
        }
    }
    if (!px || !pw || !pfpw || !pii || !pfi || n4096 != 3) return;

    const float* x       = (const float*)px;
    const int*   wpacked = (const int*)pw;
    const float* wscale  = (const float*)p4096[0];
    const float* reduced = (const float*)p4096[1];
    const float* bias    = (const float*)p4096[2];
    const float* fpw     = (const float*)pfpw;
    const int*   int_idx = (const int*)pii;
    const int*   fp_idx  = (const int*)pfi;
    float*       out     = (float*)d_out;

    const size_t NEED = (size_t)67108864 + 32768;
    if (ws_size < NEED) return;

    char* ws = (char*)d_ws;
    __hip_bfloat16* Aq = (__hip_bfloat16*)ws;                            // 32 MiB
    __hip_bfloat16* Wb = (__hip_bfloat16*)(ws + (size_t)33554432);       // 32 MiB
    float* scale_ws    = (float*)(ws + (size_t)67108864);                // 16 KiB
    float* zero_ws     = (float*)(ws + (size_t)67108864 + 16384);        // 16 KiB

    quant_kernel<<<TOKENS, 256, 0, stream>>>(x, int_idx, fp_idx, Aq, scale_ws, zero_ws);
    unpack_kernel<<<OUT_FEAT, 256, 0, stream>>>(wpacked, fpw, wscale, Wb);
    dim3 grid(TOKENS / 128, OUT_FEAT / 128);
    gemm_kernel<<<grid, 256, 0, stream>>>(Aq, Wb, scale_ws, zero_ws,
                                          wscale, reduced, bias, out);
}

// Round 7
// 152.694 us; speedup vs baseline: 2.2872x; 1.4498x over previous
//
#include <hip/hip_runtime.h>
#include <hip/hip_bf16.h>

#define IN_FEAT 4096
#define OUT_FEAT 4096
#define FP_FEAT 256
#define INT_FEAT 3840
#define TOKENS 4096
#define PACKED_W (INT_FEAT / 2)  // 1920

typedef __attribute__((ext_vector_type(8))) short short8;
typedef __attribute__((ext_vector_type(4))) float f32x4;

// ---------------------------------------------------------------- quantize ---
__global__ __launch_bounds__(256) void quant_kernel(
    const float* __restrict__ x,
    const int* __restrict__ int_idx_raw,
    const int* __restrict__ fp_idx_raw,
    __hip_bfloat16* __restrict__ Aq,
    float* __restrict__ scale_ws,
    float* __restrict__ zero_ws)
{
    const int m = blockIdx.x;
    const int t = threadIdx.x;
    const float* xr = x + (size_t)m * IN_FEAT;

    const bool is64 = (int_idx_raw[1] == 0) && (int_idx_raw[3] == 0);

    float v[15];
    float mn = 1e30f, mx = -1e30f;
#pragma unroll
    for (int j = 0; j < 15; ++j) {
        int k = t + j * 256;
        int idx = is64 ? int_idx_raw[2 * k] : int_idx_raw[k];
        float f = xr[idx];
        v[j] = f;
        mn = fminf(mn, f);
        mx = fmaxf(mx, f);
    }
#pragma unroll
    for (int off = 1; off < 64; off <<= 1) {
        mn = fminf(mn, __shfl_xor(mn, off));
        mx = fmaxf(mx, __shfl_xor(mx, off));
    }
    __shared__ float smn[4], smx[4];
    int wid = t >> 6, lane = t & 63;
    if (lane == 0) { smn[wid] = mn; smx[wid] = mx; }
    __syncthreads();
    if (t == 0) {
        float rmn = fminf(fminf(smn[0], smn[1]), fminf(smn[2], smn[3]));
        float rmx = fmaxf(fmaxf(smx[0], smx[1]), fmaxf(smx[2], smx[3]));
        float sc = fmaxf((rmx - rmn) / 15.0f, 1e-8f);
        smn[0] = rmn;
        smx[0] = sc;
        scale_ws[m] = sc;
        zero_ws[m] = rmn;
    }
    __syncthreads();
    const float zero = smn[0];
    const float sc = smx[0];

    __hip_bfloat16* ar = Aq + (size_t)m * IN_FEAT;
#pragma unroll
    for (int j = 0; j < 15; ++j) {
        int k = t + j * 256;
        float q = rintf((v[j] - zero) / sc) - 8.0f;
        q = fminf(fmaxf(q, -8.0f), 7.0f);
        ar[k] = __float2bfloat16(q);
    }
    int fpi = is64 ? fp_idx_raw[2 * t] : fp_idx_raw[t];
    ar[INT_FEAT + t] = __float2bfloat16(xr[fpi] / sc);   // fp cols pre-divided
}

// ------------------------------------------------------------ weight unpack --
__global__ __launch_bounds__(256) void unpack_kernel(
    const int* __restrict__ wpacked_raw,
    const float* __restrict__ fpw,
    const float* __restrict__ wscale,
    __hip_bfloat16* __restrict__ Wb)
{
    const int n = blockIdx.x, t = threadIdx.x;

    bool is_i32 = true;
#pragma unroll
    for (int j = 0; j < 8; ++j) {
        unsigned w = (unsigned)wpacked_raw[j];
        if (w > 0xFFu) is_i32 = false;
    }

    __hip_bfloat16* wo = Wb + (size_t)n * IN_FEAT;
    if (is_i32) {
        const int* wr = wpacked_raw + (size_t)n * PACKED_W;
#pragma unroll
        for (int j = 0; j < 8; ++j) {
            int k = t + j * 256;
            if (k < PACKED_W) {
                int p = wr[k];
                int lo = p & 15; if (lo >= 8) lo -= 16;
                int hi = (p >> 4) & 15; if (hi >= 8) hi -= 16;
                wo[2 * k]     = __float2bfloat16((float)lo);
                wo[2 * k + 1] = __float2bfloat16((float)hi);
            }
        }
    } else {
        const unsigned char* wr = (const unsigned char*)wpacked_raw
                                  + (size_t)n * PACKED_W;
#pragma unroll
        for (int j = 0; j < 8; ++j) {
            int k = t + j * 256;
            if (k < PACKED_W) {
                int p = wr[k];
                int lo = p & 15; if (lo >= 8) lo -= 16;
                int hi = (p >> 4) & 15; if (hi >= 8) hi -= 16;
                wo[2 * k]     = __float2bfloat16((float)lo);
                wo[2 * k + 1] = __float2bfloat16((float)hi);
            }
        }
    }
    float wsn = wscale[n];
    wo[INT_FEAT + t] = __float2bfloat16(fpw[(size_t)n * FP_FEAT + t] / wsn);
}

// ------------------------------------------------------- GEMM 256x256 8-phase
// 512 thr = 8 waves (2M x 4N); per-wave out 128x64 (8x4 frags of 16x16).
// LDS 128 KiB: buf b at byte b*65536: A[256][64] bf16, then B[256][64].
// st_16x32 swizzle: byte ^= ((byte>>9)&1)<<5 -> on reads: ^ ((lane&4)<<3);
// staging keeps linear LDS dest and pre-swizzles the GLOBAL source (rule 21).
// Schedule per K-tile kt (buf = kt&1): P1 stage B(kt+1)->buf^1, read A ks0 +
// B c01 ks0, 16 MFMA; P2 read B c23 ks0, 16 MFMA; P3 read A ks1 + B c01 ks1,
// 16 MFMA; P4 stage A(kt+2)->buf, read B c23 ks1, 16 MFMA, vmcnt(4), barrier.
// Region safety: A(buf) last read P3, staged P4; B(buf^1) last read in tile
// kt-1 P4, staged kt-P1 -- both behind barriers. vmcnt(4) drains tile kt+1's
// 8 staging instrs, keeps kt+2.A (4) in flight (counted, never 0).

#define MFMA_CP(CP)                                                            \
    do {                                                                       \
        __builtin_amdgcn_s_setprio(1);                                         \
        _Pragma("unroll")                                                      \
        for (int mf = 0; mf < 8; ++mf) {                                       \
            acc[mf][2*(CP)]   = __builtin_amdgcn_mfma_f32_16x16x32_bf16(       \
                aF[mf], bF[0], acc[mf][2*(CP)], 0, 0, 0);                      \
            acc[mf][2*(CP)+1] = __builtin_amdgcn_mfma_f32_16x16x32_bf16(       \
                aF[mf], bF[1], acc[mf][2*(CP)+1], 0, 0, 0);                    \
        }                                                                      \
        __builtin_amdgcn_s_setprio(0);                                         \
    } while (0)

__global__ __launch_bounds__(512, 2) void gemm256(
    const __hip_bfloat16* __restrict__ Aq,     // [4096][4096]
    const __hip_bfloat16* __restrict__ Wb,     // [4096][4096]
    const float* __restrict__ scale_ws,
    const float* __restrict__ zero_ws,
    const float* __restrict__ wscale,
    const float* __restrict__ reduced,
    const float* __restrict__ bias,
    float* __restrict__ out)
{
    __shared__ __hip_bfloat16 lds[65536];      // 128 KiB
    char* ldsb = (char*)lds;

    const int t = threadIdx.x;
    const int lane = t & 63, wid = t >> 6;
    const int wr = wid >> 2;                   // 0..1
    const int wc = wid & 3;                    // 0..3
    const int r16 = lane & 15;
    const int kg = lane >> 4;
    const int xorb = (lane & 4) << 3;          // read-side swizzle XOR (0/32)

    // XCD-aware block swizzle (256 blocks, 8 XCDs, 32/chunk)
    const int bid = blockIdx.x;
    const int sb = (bid & 7) * 32 + (bid >> 3);
    const int tileM = (sb >> 4) * 256;
    const int tileN = (sb & 15) * 256;

    // staging source addresses (pre-swizzled global rows/cols)
    const __hip_bfloat16* srcA[4];
    const __hip_bfloat16* srcB[4];
    int cdst[4];
#pragma unroll
    for (int j = 0; j < 4; ++j) {
        int c16 = j * 512 + t;
        int lc = c16 ^ (((c16 >> 5) & 1) << 1);
        int row = lc >> 3;
        int col = (lc & 7) * 8;
        srcA[j] = Aq + (size_t)(tileM + row) * IN_FEAT + col;
        srcB[j] = Wb + (size_t)(tileN + row) * IN_FEAT + col;
        cdst[j] = c16 * 8;                     // linear LDS dest (elems)
    }

    auto stageA = [&](int ktile, int bufe) {   // bufe: buf*32768 (elems)
#pragma unroll
        for (int j = 0; j < 4; ++j)
            __builtin_amdgcn_global_load_lds(
                (const __attribute__((address_space(1))) void*)(srcA[j] + ktile * 64),
                (__attribute__((address_space(3))) void*)&lds[bufe + cdst[j]],
                16, 0, 0);
    };
    auto stageB = [&](int ktile, int bufe) {
#pragma unroll
        for (int j = 0; j < 4; ++j)
            __builtin_amdgcn_global_load_lds(
                (const __attribute__((address_space(1))) void*)(srcB[j] + ktile * 64),
                (__attribute__((address_space(3))) void*)&lds[bufe + 16384 + cdst[j]],
                16, 0, 0);
    };

    f32x4 acc[8][4];
#pragma unroll
    for (int mf = 0; mf < 8; ++mf)
#pragma unroll
        for (int nf = 0; nf < 4; ++nf)
            acc[mf][nf] = (f32x4){0.f, 0.f, 0.f, 0.f};

    short8 aF[8], bF[2];

    auto loadA = [&](int bufo, int ks) {       // bufo: buf*65536 (bytes)
#pragma unroll
        for (int mf = 0; mf < 8; ++mf)
            aF[mf] = *(const short8*)(ldsb + bufo
                        + (wr * 128 + mf * 16 + r16) * 128
                        + ((ks * 64 + kg * 16) ^ xorb));
    };
    auto loadB = [&](int bufo, int cp, int ks) {
#pragma unroll
        for (int q = 0; q < 2; ++q)
            bF[q] = *(const short8*)(ldsb + bufo + 32768
                        + (wc * 64 + (cp * 2 + q) * 16 + r16) * 128
                        + ((ks * 64 + kg * 16) ^ xorb));
    };

    // prologue: tile0.A, tile0.B, tile1.A ; wait tile0 landed (keep 1.A flying)
    stageA(0, 0);
    stageB(0, 0);
    stageA(1, 32768);
    asm volatile("s_waitcnt vmcnt(4)" ::: "memory");
    __builtin_amdgcn_s_barrier();

    for (int kt = 0; kt < 64; ++kt) {
        const int buf = kt & 1;
        const int bufo = buf << 16;            // bytes
        const int bufe = buf << 15;            // elems
        const int nbufe = bufe ^ 32768;

        // P1: stage B(kt+1) -> other buf; compute ks0, cols 0-31
        stageB((kt + 1) & 63, nbufe);
        loadA(bufo, 0);
        loadB(bufo, 0, 0);
        MFMA_CP(0);
        __builtin_amdgcn_s_barrier();

        // P2: ks0, cols 32-63
        loadB(bufo, 1, 0);
        MFMA_CP(1);
        __builtin_amdgcn_s_barrier();

        // P3: ks1, cols 0-31
        loadA(bufo, 1);
        loadB(bufo, 0, 1);
        MFMA_CP(0);
        __builtin_amdgcn_s_barrier();

        // P4: stage A(kt+2) -> this buf; ks1, cols 32-63; counted vmcnt
        stageA((kt + 2) & 63, bufe);
        loadB(bufo, 1, 1);
        MFMA_CP(1);
        asm volatile("s_waitcnt vmcnt(4)" ::: "memory");
        __builtin_amdgcn_s_barrier();
    }

    // epilogue: out = sc*ws*acc + (zero + 8*sc)*reduced + bias
    const int cr4 = kg * 4;
#pragma unroll
    for (int mf = 0; mf < 8; ++mf) {
#pragma unroll
        for (int nf = 0; nf < 4; ++nf) {
            int n = tileN + wc * 64 + nf * 16 + r16;
            float ws = wscale[n];
            float rd = reduced[n];
            float bs = bias[n];
#pragma unroll
            for (int i = 0; i < 4; ++i) {
                int m = tileM + wr * 128 + mf * 16 + cr4 + i;
                float sc = scale_ws[m];
                float zr = zero_ws[m];
                out[(size_t)m * OUT_FEAT + n] =
                    sc * ws * acc[mf][nf][i]
                    + (zr + sc * 8.0f) * rd + bs;
            }
        }
    }
}

// ------------------------------------------------------------------ launch ---
extern "C" void kernel_launch(void* const* d_in, const int* in_sizes, int n_in,
                              void* d_out, int out_size, void* d_ws, size_t ws_size,
                              hipStream_t stream)
{
    const void* px = 0; const void* pw = 0; const void* pfpw = 0;
    const void* pii = 0; const void* pfi = 0;
    const void* p4096[3] = {0, 0, 0}; int n4096 = 0;
    for (int i = 0; i < n_in; ++i) {
        switch (in_sizes[i]) {
            case 16777216: px = d_in[i]; break;
            case 7864320:  pw = d_in[i]; break;
            case 1048576:  pfpw = d_in[i]; break;
            case 3840:     pii = d_in[i]; break;
            case 256:      pfi = d_in[i]; break;
            case 4096:     if (n4096 < 3) p4096[n4096++] = d_in[i]; break;
            default: break;
        }
    }
    if (!px || !pw || !pfpw || !pii || !pfi || n4096 != 3) return;

    const float* x       = (const float*)px;
    const int*   wpacked = (const int*)pw;
    const float* wscale  = (const float*)p4096[0];
    const float* reduced = (const float*)p4096[1];
    const float* bias    = (const float*)p4096[2];
    const float* fpw     = (const float*)pfpw;
    const int*   int_idx = (const int*)pii;
    const int*   fp_idx  = (const int*)pfi;
    float*       out     = (float*)d_out;

    const size_t NEED = (size_t)67108864 + 32768;
    if (ws_size < NEED) return;

    char* ws = (char*)d_ws;
    __hip_bfloat16* Aq = (__hip_bfloat16*)ws;                            // 32 MiB
    __hip_bfloat16* Wb = (__hip_bfloat16*)(ws + (size_t)33554432);       // 32 MiB
    float* scale_ws    = (float*)(ws + (size_t)67108864);                // 16 KiB
    float* zero_ws     = (float*)(ws + (size_t)67108864 + 16384);        // 16 KiB

    quant_kernel<<<TOKENS, 256, 0, stream>>>(x, int_idx, fp_idx, Aq, scale_ws, zero_ws);
    unpack_kernel<<<OUT_FEAT, 256, 0, stream>>>(wpacked, fpw, wscale, Wb);
    gemm256<<<256, 512, 0, stream>>>(Aq, Wb, scale_ws, zero_ws,
                                     wscale, reduced, bias, out);
}

// Round 8
// 148.009 us; speedup vs baseline: 2.3596x; 1.0317x over previous
//
#include <hip/hip_runtime.h>
#include <hip/hip_bf16.h>

#define IN_FEAT 4096
#define OUT_FEAT 4096
#define FP_FEAT 256
#define INT_FEAT 3840
#define TOKENS 4096
#define PACKED_W (INT_FEAT / 2)  // 1920

typedef __attribute__((ext_vector_type(8))) short short8;
typedef __attribute__((ext_vector_type(4))) float f32x4;

// ---------------------------------------------------------------- quantize ---
__global__ __launch_bounds__(256) void quant_kernel(
    const float* __restrict__ x,
    const int* __restrict__ int_idx_raw,
    const int* __restrict__ fp_idx_raw,
    __hip_bfloat16* __restrict__ Aq,
    float* __restrict__ scale_ws,
    float* __restrict__ zero_ws)
{
    const int m = blockIdx.x;
    const int t = threadIdx.x;
    const float* xr = x + (size_t)m * IN_FEAT;

    const bool is64 = (int_idx_raw[1] == 0) && (int_idx_raw[3] == 0);

    float v[15];
    float mn = 1e30f, mx = -1e30f;
#pragma unroll
    for (int j = 0; j < 15; ++j) {
        int k = t + j * 256;
        int idx = is64 ? int_idx_raw[2 * k] : int_idx_raw[k];
        float f = xr[idx];
        v[j] = f;
        mn = fminf(mn, f);
        mx = fmaxf(mx, f);
    }
#pragma unroll
    for (int off = 1; off < 64; off <<= 1) {
        mn = fminf(mn, __shfl_xor(mn, off));
        mx = fmaxf(mx, __shfl_xor(mx, off));
    }
    __shared__ float smn[4], smx[4];
    int wid = t >> 6, lane = t & 63;
    if (lane == 0) { smn[wid] = mn; smx[wid] = mx; }
    __syncthreads();
    if (t == 0) {
        float rmn = fminf(fminf(smn[0], smn[1]), fminf(smn[2], smn[3]));
        float rmx = fmaxf(fmaxf(smx[0], smx[1]), fmaxf(smx[2], smx[3]));
        float sc = fmaxf((rmx - rmn) / 15.0f, 1e-8f);
        smn[0] = rmn;
        smx[0] = sc;
        scale_ws[m] = sc;
        zero_ws[m] = rmn;
    }
    __syncthreads();
    const float zero = smn[0];
    const float sc = smx[0];

    __hip_bfloat16* ar = Aq + (size_t)m * IN_FEAT;
#pragma unroll
    for (int j = 0; j < 15; ++j) {
        int k = t + j * 256;
        float q = rintf((v[j] - zero) / sc) - 8.0f;
        q = fminf(fmaxf(q, -8.0f), 7.0f);
        ar[k] = __float2bfloat16(q);
    }
    int fpi = is64 ? fp_idx_raw[2 * t] : fp_idx_raw[t];
    ar[INT_FEAT + t] = __float2bfloat16(xr[fpi] / sc);   // fp cols pre-divided
}

// ------------------------------------------------------------ weight unpack --
__global__ __launch_bounds__(256) void unpack_kernel(
    const int* __restrict__ wpacked_raw,
    const float* __restrict__ fpw,
    const float* __restrict__ wscale,
    __hip_bfloat16* __restrict__ Wb)
{
    const int n = blockIdx.x, t = threadIdx.x;

    bool is_i32 = true;
#pragma unroll
    for (int j = 0; j < 8; ++j) {
        unsigned w = (unsigned)wpacked_raw[j];
        if (w > 0xFFu) is_i32 = false;
    }

    __hip_bfloat16* wo = Wb + (size_t)n * IN_FEAT;
    if (is_i32) {
        const int* wr = wpacked_raw + (size_t)n * PACKED_W;
#pragma unroll
        for (int j = 0; j < 8; ++j) {
            int k = t + j * 256;
            if (k < PACKED_W) {
                int p = wr[k];
                int lo = p & 15; if (lo >= 8) lo -= 16;
                int hi = (p >> 4) & 15; if (hi >= 8) hi -= 16;
                wo[2 * k]     = __float2bfloat16((float)lo);
                wo[2 * k + 1] = __float2bfloat16((float)hi);
            }
        }
    } else {
        const unsigned char* wr = (const unsigned char*)wpacked_raw
                                  + (size_t)n * PACKED_W;
#pragma unroll
        for (int j = 0; j < 8; ++j) {
            int k = t + j * 256;
            if (k < PACKED_W) {
                int p = wr[k];
                int lo = p & 15; if (lo >= 8) lo -= 16;
                int hi = (p >> 4) & 15; if (hi >= 8) hi -= 16;
                wo[2 * k]     = __float2bfloat16((float)lo);
                wo[2 * k + 1] = __float2bfloat16((float)hi);
            }
        }
    }
    float wsn = wscale[n];
    wo[INT_FEAT + t] = __float2bfloat16(fpw[(size_t)n * FP_FEAT + t] / wsn);
}

// ------------------------------------------------------- GEMM 256x256 8-phase
// 512 thr = 8 waves (2M x 4N); per-wave out 128x64. LDS 128 KiB, 2 buffers.
// 3-bit swizzle: within each 128B row, 16B slot s holds k-slot s^(row&7);
// staging keeps LINEAR LDS dest and inverse-permutes the GLOBAL source
// (rule 21); reads XOR the k-byte offset with (r16&7)<<4 -> 2 lanes/slot
// per quarter-wave phase -> conflict-free ds_read_b128.
// Phase discipline (m201): {ds_read issue; stage issue; sched_barrier;
// s_barrier; lgkm (compiler); setprio(1); 16 MFMA; setprio(0); s_barrier}.
// vmcnt(4) only at P4 (counted, never 0): drains A(kt+1),B(kt+1), keeps
// A(kt+2) in flight. Region audit: A(buf) last read P3 (complete at P3
// end-bar), staged P4; B(buf^1) last read prev-tile P4, staged P1.

#define MFMA_CP(CP)                                                            \
    do {                                                                       \
        __builtin_amdgcn_s_setprio(1);                                         \
        _Pragma("unroll")                                                      \
        for (int mf = 0; mf < 8; ++mf) {                                       \
            acc[mf][2*(CP)]   = __builtin_amdgcn_mfma_f32_16x16x32_bf16(       \
                aF[mf], bF[0], acc[mf][2*(CP)], 0, 0, 0);                      \
            acc[mf][2*(CP)+1] = __builtin_amdgcn_mfma_f32_16x16x32_bf16(       \
                aF[mf], bF[1], acc[mf][2*(CP)+1], 0, 0, 0);                    \
        }                                                                      \
        __builtin_amdgcn_s_setprio(0);                                         \
    } while (0)

__global__ __launch_bounds__(512, 2) void gemm256(
    const __hip_bfloat16* __restrict__ Aq,     // [4096][4096]
    const __hip_bfloat16* __restrict__ Wb,     // [4096][4096]
    const float* __restrict__ scale_ws,
    const float* __restrict__ zero_ws,
    const float* __restrict__ wscale,
    const float* __restrict__ reduced,
    const float* __restrict__ bias,
    float* __restrict__ out)
{
    __shared__ __hip_bfloat16 lds[65536];      // 128 KiB
    char* ldsb = (char*)lds;

    const int t = threadIdx.x;
    const int lane = t & 63, wid = t >> 6;
    const int wr = wid >> 2;                   // 0..1
    const int wc = wid & 3;                    // 0..3
    const int r16 = lane & 15;
    const int kg = lane >> 4;
    const int xorb = (r16 & 7) << 4;           // 3-bit read-side swizzle XOR

    // XCD-aware block swizzle (256 blocks, 8 XCDs, 32/chunk)
    const int bid = blockIdx.x;
    const int sb = (bid & 7) * 32 + (bid >> 3);
    const int tileM = (sb >> 4) * 256;
    const int tileN = (sb & 15) * 256;

    // staging: linear LDS dest c16*16B; global source inverse-permuted
    const __hip_bfloat16* srcA[4];
    const __hip_bfloat16* srcB[4];
    int cdst[4];
#pragma unroll
    for (int j = 0; j < 4; ++j) {
        int c16 = j * 512 + t;
        int row = c16 >> 3;                    // 0..255
        int col8 = (c16 & 7) ^ (row & 7);      // inverse swizzle
        srcA[j] = Aq + (size_t)(tileM + row) * IN_FEAT + col8 * 8;
        srcB[j] = Wb + (size_t)(tileN + row) * IN_FEAT + col8 * 8;
        cdst[j] = c16 * 8;                     // linear LDS dest (elems)
    }

    auto stageA = [&](int ktile, int bufe) {
#pragma unroll
        for (int j = 0; j < 4; ++j)
            __builtin_amdgcn_global_load_lds(
                (const __attribute__((address_space(1))) void*)(srcA[j] + ktile * 64),
                (__attribute__((address_space(3))) void*)&lds[bufe + cdst[j]],
                16, 0, 0);
    };
    auto stageB = [&](int ktile, int bufe) {
#pragma unroll
        for (int j = 0; j < 4; ++j)
            __builtin_amdgcn_global_load_lds(
                (const __attribute__((address_space(1))) void*)(srcB[j] + ktile * 64),
                (__attribute__((address_space(3))) void*)&lds[bufe + 16384 + cdst[j]],
                16, 0, 0);
    };

    f32x4 acc[8][4];
#pragma unroll
    for (int mf = 0; mf < 8; ++mf)
#pragma unroll
        for (int nf = 0; nf < 4; ++nf)
            acc[mf][nf] = (f32x4){0.f, 0.f, 0.f, 0.f};

    short8 aF[8], bF[2];

    auto loadA = [&](int bufo, int ks) {
#pragma unroll
        for (int mf = 0; mf < 8; ++mf)
            aF[mf] = *(const short8*)(ldsb + bufo
                        + (wr * 128 + mf * 16 + r16) * 128
                        + ((ks * 64 + kg * 16) ^ xorb));
    };
    auto loadB = [&](int bufo, int cp, int ks) {
#pragma unroll
        for (int q = 0; q < 2; ++q)
            bF[q] = *(const short8*)(ldsb + bufo + 32768
                        + (wc * 64 + (cp * 2 + q) * 16 + r16) * 128
                        + ((ks * 64 + kg * 16) ^ xorb));
    };

    // prologue: tile0.A, tile0.B, tile1.A; drain tile0, keep 1.A in flight
    stageA(0, 0);
    stageB(0, 0);
    stageA(1, 32768);
    asm volatile("s_waitcnt vmcnt(4)" ::: "memory");
    __builtin_amdgcn_s_barrier();

    for (int kt = 0; kt < 64; ++kt) {
        const int buf = kt & 1;
        const int bufo = buf << 16;            // bytes
        const int bufe = buf << 15;            // elems
        const int nbufe = bufe ^ 32768;

        // P1: read A ks0 + B c01 ks0; stage B(kt+1) -> other buf
        loadA(bufo, 0);
        loadB(bufo, 0, 0);
        stageB((kt + 1) & 63, nbufe);
        __builtin_amdgcn_sched_barrier(0);
        __builtin_amdgcn_s_barrier();
        MFMA_CP(0);
        __builtin_amdgcn_s_barrier();

        // P2: read B c23 ks0
        loadB(bufo, 1, 0);
        __builtin_amdgcn_sched_barrier(0);
        __builtin_amdgcn_s_barrier();
        MFMA_CP(1);
        __builtin_amdgcn_s_barrier();

        // P3: read A ks1 + B c01 ks1
        loadA(bufo, 1);
        loadB(bufo, 0, 1);
        __builtin_amdgcn_sched_barrier(0);
        __builtin_amdgcn_s_barrier();
        MFMA_CP(0);
        __builtin_amdgcn_s_barrier();

        // P4: read B c23 ks1; stage A(kt+2) -> this buf; counted vmcnt
        loadB(bufo, 1, 1);
        stageA((kt + 2) & 63, bufe);
        asm volatile("s_waitcnt vmcnt(4)" ::: "memory");
        __builtin_amdgcn_sched_barrier(0);
        __builtin_amdgcn_s_barrier();
        MFMA_CP(1);
        __builtin_amdgcn_s_barrier();
    }

    // epilogue: out = sc*ws*acc + (zero + 8*sc)*reduced + bias
    const int cr4 = kg * 4;
#pragma unroll
    for (int mf = 0; mf < 8; ++mf) {
#pragma unroll
        for (int nf = 0; nf < 4; ++nf) {
            int n = tileN + wc * 64 + nf * 16 + r16;
            float ws = wscale[n];
            float rd = reduced[n];
            float bs = bias[n];
#pragma unroll
            for (int i = 0; i < 4; ++i) {
                int m = tileM + wr * 128 + mf * 16 + cr4 + i;
                float sc = scale_ws[m];
                float zr = zero_ws[m];
                out[(size_t)m * OUT_FEAT + n] =
                    sc * ws * acc[mf][nf][i]
                    + (zr + sc * 8.0f) * rd + bs;
            }
        }
    }
}

// ------------------------------------------------------------------ launch ---
extern "C" void kernel_launch(void* const* d_in, const int* in_sizes, int n_in,
                              void* d_out, int out_size, void* d_ws, size_t ws_size,
                              hipStream_t stream)
{
    const void* px = 0; const void* pw = 0; const void* pfpw = 0;
    const void* pii = 0; const void* pfi = 0;
    const void* p4096[3] = {0, 0, 0}; int n4096 = 0;
    for (int i = 0; i < n_in; ++i) {
        switch (in_sizes[i]) {
            case 16777216: px = d_in[i]; break;
            case 7864320:  pw = d_in[i]; break;
            case 1048576:  pfpw = d_in[i]; break;
            case 3840:     pii = d_in[i]; break;
            case 256:      pfi = d_in[i]; break;
            case 4096:     if (n4096 < 3) p4096[n4096++] = d_in[i]; break;
            default: break;
        }
    }
    if (!px || !pw || !pfpw || !pii || !pfi || n4096 != 3) return;

    const float* x       = (const float*)px;
    const int*   wpacked = (const int*)pw;
    const float* wscale  = (const float*)p4096[0];
    const float* reduced = (const float*)p4096[1];
    const float* bias    = (const float*)p4096[2];
    const float* fpw     = (const float*)pfpw;
    const int*   int_idx = (const int*)pii;
    const int*   fp_idx  = (const int*)pfi;
    float*       out     = (float*)d_out;

    const size_t NEED = (size_t)67108864 + 32768;
    if (ws_size < NEED) return;

    char* ws = (char*)d_ws;
    __hip_bfloat16* Aq = (__hip_bfloat16*)ws;                            // 32 MiB
    __hip_bfloat16* Wb = (__hip_bfloat16*)(ws + (size_t)33554432);       // 32 MiB
    float* scale_ws    = (float*)(ws + (size_t)67108864);                // 16 KiB
    float* zero_ws     = (float*)(ws + (size_t)67108864 + 16384);        // 16 KiB

    quant_kernel<<<TOKENS, 256, 0, stream>>>(x, int_idx, fp_idx, Aq, scale_ws, zero_ws);
    unpack_kernel<<<OUT_FEAT, 256, 0, stream>>>(wpacked, fpw, wscale, Wb);
    gemm256<<<256, 512, 0, stream>>>(Aq, Wb, scale_ws, zero_ws,
                                     wscale, reduced, bias, out);
}

// Round 9
// 146.032 us; speedup vs baseline: 2.3916x; 1.0135x over previous
//
#include <hip/hip_runtime.h>
#include <hip/hip_bf16.h>

#define IN_FEAT 4096
#define OUT_FEAT 4096
#define FP_FEAT 256
#define INT_FEAT 3840
#define TOKENS 4096
#define PACKED_W (INT_FEAT / 2)  // 1920

typedef __attribute__((ext_vector_type(8))) short short8;
typedef __attribute__((ext_vector_type(4))) float f32x4;

// ------------------------------------------------- fused quantize + unpack ---
// blocks 0..4095: quantize token row m; blocks 4096..8191: unpack weight row.
__global__ __launch_bounds__(256) void prep_kernel(
    const float* __restrict__ x,
    const int* __restrict__ int_idx_raw,
    const int* __restrict__ fp_idx_raw,
    const int* __restrict__ wpacked_raw,
    const float* __restrict__ fpw,
    const float* __restrict__ wscale,
    __hip_bfloat16* __restrict__ Aq,
    __hip_bfloat16* __restrict__ Wb,
    float* __restrict__ scale_ws,
    float* __restrict__ zero_ws)
{
    const int t = threadIdx.x;
    if (blockIdx.x < TOKENS) {
        // ---------------- quant path ----------------
        const int m = blockIdx.x;
        const float* xr = x + (size_t)m * IN_FEAT;
        const bool is64 = (int_idx_raw[1] == 0) && (int_idx_raw[3] == 0);

        float v[15];
        float mn = 1e30f, mx = -1e30f;
#pragma unroll
        for (int j = 0; j < 15; ++j) {
            int k = t + j * 256;
            int idx = is64 ? int_idx_raw[2 * k] : int_idx_raw[k];
            float f = xr[idx];
            v[j] = f;
            mn = fminf(mn, f);
            mx = fmaxf(mx, f);
        }
#pragma unroll
        for (int off = 1; off < 64; off <<= 1) {
            mn = fminf(mn, __shfl_xor(mn, off));
            mx = fmaxf(mx, __shfl_xor(mx, off));
        }
        __shared__ float smn[4], smx[4];
        int wid = t >> 6, lane = t & 63;
        if (lane == 0) { smn[wid] = mn; smx[wid] = mx; }
        __syncthreads();
        if (t == 0) {
            float rmn = fminf(fminf(smn[0], smn[1]), fminf(smn[2], smn[3]));
            float rmx = fmaxf(fmaxf(smx[0], smx[1]), fmaxf(smx[2], smx[3]));
            float sc = fmaxf((rmx - rmn) / 15.0f, 1e-8f);
            smn[0] = rmn;
            smx[0] = sc;
            scale_ws[m] = sc;
            zero_ws[m] = rmn;
        }
        __syncthreads();
        const float zero = smn[0];
        const float sc = smx[0];

        __hip_bfloat16* ar = Aq + (size_t)m * IN_FEAT;
#pragma unroll
        for (int j = 0; j < 15; ++j) {
            int k = t + j * 256;
            float q = rintf((v[j] - zero) / sc) - 8.0f;   // IEEE div+rndne == np
            q = fminf(fmaxf(q, -8.0f), 7.0f);
            ar[k] = __float2bfloat16(q);                  // exact small int
        }
        int fpi = is64 ? fp_idx_raw[2 * t] : fp_idx_raw[t];
        ar[INT_FEAT + t] = __float2bfloat16(xr[fpi] / sc);   // fp cols / sc_m
    } else {
        // ---------------- unpack path ----------------
        const int n = blockIdx.x - TOKENS;
        bool is_i32 = true;
#pragma unroll
        for (int j = 0; j < 8; ++j) {
            unsigned w = (unsigned)wpacked_raw[j];
            if (w > 0xFFu) is_i32 = false;
        }
        __hip_bfloat16* wo = Wb + (size_t)n * IN_FEAT;
        if (is_i32) {
            const int* wr = wpacked_raw + (size_t)n * PACKED_W;
#pragma unroll
            for (int j = 0; j < 8; ++j) {
                int k = t + j * 256;
                if (k < PACKED_W) {
                    int p = wr[k];
                    int lo = p & 15; if (lo >= 8) lo -= 16;
                    int hi = (p >> 4) & 15; if (hi >= 8) hi -= 16;
                    wo[2 * k]     = __float2bfloat16((float)lo);
                    wo[2 * k + 1] = __float2bfloat16((float)hi);
                }
            }
        } else {
            const unsigned char* wr = (const unsigned char*)wpacked_raw
                                      + (size_t)n * PACKED_W;
#pragma unroll
            for (int j = 0; j < 8; ++j) {
                int k = t + j * 256;
                if (k < PACKED_W) {
                    int p = wr[k];
                    int lo = p & 15; if (lo >= 8) lo -= 16;
                    int hi = (p >> 4) & 15; if (hi >= 8) hi -= 16;
                    wo[2 * k]     = __float2bfloat16((float)lo);
                    wo[2 * k + 1] = __float2bfloat16((float)hi);
                }
            }
        }
        float wsn = wscale[n];
        wo[INT_FEAT + t] = __float2bfloat16(fpw[(size_t)n * FP_FEAT + t] / wsn);
    }
}

// ------------------------------------------------------- GEMM 256x256 2-phase
// 512 thr = 8 waves (2M x 4N); per-wave out 128x64. LDS 128 KiB, 2 buffers.
// 3-bit swizzle (conflict-free, verified r8): linear gload_lds dest,
// inverse-permuted global source, read-side byte XOR (r16&7)<<4.
// 2 phases per K-tile, 32 MFMA per phase:
//  Ph1: read A ks0 (8) + B ks0 (4); stage B(kt+1)->nbuf; bar; 32 MFMA; bar.
//  Ph2: read A ks1 + B ks1; lgkmcnt(0); bar; stage A(kt+2)->buf; 32 MFMA;
//       vmcnt(4); bar.
// Hazards: nbuf.B last read kt-1 Ph2 (done before its mid-bar lgkm) ->
// stage at kt Ph1 safe. buf.A reads: ks0 done before Ph1 MFMA consumption
// (end-bar), ks1 done via explicit lgkm before Ph2 mid-bar -> stage after
// mid-bar safe. vmcnt(4) (in-order retire): drains A(kt+1),B(kt+1), keeps
// A(kt+2) in flight -- counted, never 0. Per-acc K order (ks0,ks1 per kt)
// identical to r8 -> absmax must stay bit-exact 0.1992188.

#define MFMA_ALL()                                                             \
    do {                                                                       \
        __builtin_amdgcn_s_setprio(1);                                         \
        _Pragma("unroll")                                                      \
        for (int mf = 0; mf < 8; ++mf)                                         \
            _Pragma("unroll")                                                  \
            for (int nf = 0; nf < 4; ++nf)                                     \
                acc[mf][nf] = __builtin_amdgcn_mfma_f32_16x16x32_bf16(         \
                    aF[mf], bF[nf], acc[mf][nf], 0, 0, 0);                     \
        __builtin_amdgcn_s_setprio(0);                                         \
    } while (0)

__global__ __launch_bounds__(512, 2) void gemm256(
    const __hip_bfloat16* __restrict__ Aq,
    const __hip_bfloat16* __restrict__ Wb,
    const float* __restrict__ scale_ws,
    const float* __restrict__ zero_ws,
    const float* __restrict__ wscale,
    const float* __restrict__ reduced,
    const float* __restrict__ bias,
    float* __restrict__ out)
{
    __shared__ __hip_bfloat16 lds[65536];      // 128 KiB
    char* ldsb = (char*)lds;

    const int t = threadIdx.x;
    const int lane = t & 63, wid = t >> 6;
    const int wr = wid >> 2;                   // 0..1
    const int wc = wid & 3;                    // 0..3
    const int r16 = lane & 15;
    const int kg = lane >> 4;
    const int xorb = (r16 & 7) << 4;           // 3-bit read-side swizzle XOR

    // XCD-aware block swizzle (256 blocks, 8 XCDs, 32/chunk)
    const int bid = blockIdx.x;
    const int sb = (bid & 7) * 32 + (bid >> 3);
    const int tileM = (sb >> 4) * 256;
    const int tileN = (sb & 15) * 256;

    // staging: linear LDS dest c16*16B; global source inverse-permuted
    const __hip_bfloat16* srcA[4];
    const __hip_bfloat16* srcB[4];
    int cdst[4];
#pragma unroll
    for (int j = 0; j < 4; ++j) {
        int c16 = j * 512 + t;
        int row = c16 >> 3;                    // 0..255
        int col8 = (c16 & 7) ^ (row & 7);      // inverse swizzle
        srcA[j] = Aq + (size_t)(tileM + row) * IN_FEAT + col8 * 8;
        srcB[j] = Wb + (size_t)(tileN + row) * IN_FEAT + col8 * 8;
        cdst[j] = c16 * 8;
    }

    auto stageA = [&](int ktile, int bufe) {
#pragma unroll
        for (int j = 0; j < 4; ++j)
            __builtin_amdgcn_global_load_lds(
                (const __attribute__((address_space(1))) void*)(srcA[j] + ktile * 64),
                (__attribute__((address_space(3))) void*)&lds[bufe + cdst[j]],
                16, 0, 0);
    };
    auto stageB = [&](int ktile, int bufe) {
#pragma unroll
        for (int j = 0; j < 4; ++j)
            __builtin_amdgcn_global_load_lds(
                (const __attribute__((address_space(1))) void*)(srcB[j] + ktile * 64),
                (__attribute__((address_space(3))) void*)&lds[bufe + 16384 + cdst[j]],
                16, 0, 0);
    };

    f32x4 acc[8][4];
#pragma unroll
    for (int mf = 0; mf < 8; ++mf)
#pragma unroll
        for (int nf = 0; nf < 4; ++nf)
            acc[mf][nf] = (f32x4){0.f, 0.f, 0.f, 0.f};

    short8 aF[8], bF[4];

    auto loadA = [&](int bufo, int ks) {
#pragma unroll
        for (int mf = 0; mf < 8; ++mf)
            aF[mf] = *(const short8*)(ldsb + bufo
                        + (wr * 128 + mf * 16 + r16) * 128
                        + ((ks * 64 + kg * 16) ^ xorb));
    };
    auto loadB = [&](int bufo, int ks) {
#pragma unroll
        for (int nf = 0; nf < 4; ++nf)
            bF[nf] = *(const short8*)(ldsb + bufo + 32768
                        + (wc * 64 + nf * 16 + r16) * 128
                        + ((ks * 64 + kg * 16) ^ xorb));
    };

    // prologue: tile0.A, tile0.B, tile1.A; drain tile0, keep 1.A in flight
    stageA(0, 0);
    stageB(0, 0);
    stageA(1, 32768);
    asm volatile("s_waitcnt vmcnt(4)" ::: "memory");
    __builtin_amdgcn_s_barrier();

    for (int kt = 0; kt < 64; ++kt) {
        const int buf = kt & 1;
        const int bufo = buf << 16;            // bytes
        const int bufe = buf << 15;            // elems
        const int nbufe = bufe ^ 32768;

        // Ph1: read ks0; stage next B; 32 MFMA
        loadA(bufo, 0);
        loadB(bufo, 0);
        stageB((kt + 1) & 63, nbufe);
        __builtin_amdgcn_sched_barrier(0);
        __builtin_amdgcn_s_barrier();
        MFMA_ALL();                            // compiler lgkm waits feed MFMA
        __builtin_amdgcn_s_barrier();

        // Ph2: read ks1; all-wave lgkm drain; stage A(kt+2); 32 MFMA; vmcnt(4)
        loadA(bufo, 1);
        loadB(bufo, 1);
        asm volatile("s_waitcnt lgkmcnt(0)" ::: "memory");
        __builtin_amdgcn_sched_barrier(0);
        __builtin_amdgcn_s_barrier();
        stageA((kt + 2) & 63, bufe);
        MFMA_ALL();
        asm volatile("s_waitcnt vmcnt(4)" ::: "memory");
        __builtin_amdgcn_s_barrier();
    }

    // epilogue: out = sc*ws*acc + (zero + 8*sc)*reduced + bias
    const int cr4 = kg * 4;
#pragma unroll
    for (int mf = 0; mf < 8; ++mf) {
#pragma unroll
        for (int nf = 0; nf < 4; ++nf) {
            int n = tileN + wc * 64 + nf * 16 + r16;
            float ws = wscale[n];
            float rd = reduced[n];
            float bs = bias[n];
#pragma unroll
            for (int i = 0; i < 4; ++i) {
                int m = tileM + wr * 128 + mf * 16 + cr4 + i;
                float sc = scale_ws[m];
                float zr = zero_ws[m];
                out[(size_t)m * OUT_FEAT + n] =
                    sc * ws * acc[mf][nf][i]
                    + (zr + sc * 8.0f) * rd + bs;
            }
        }
    }
}

// ------------------------------------------------------------------ launch ---
extern "C" void kernel_launch(void* const* d_in, const int* in_sizes, int n_in,
                              void* d_out, int out_size, void* d_ws, size_t ws_size,
                              hipStream_t stream)
{
    const void* px = 0; const void* pw = 0; const void* pfpw = 0;
    const void* pii = 0; const void* pfi = 0;
    const void* p4096[3] = {0, 0, 0}; int n4096 = 0;
    for (int i = 0; i < n_in; ++i) {
        switch (in_sizes[i]) {
            case 16777216: px = d_in[i]; break;
            case 7864320:  pw = d_in[i]; break;
            case 1048576:  pfpw = d_in[i]; break;
            case 3840:     pii = d_in[i]; break;
            case 256:      pfi = d_in[i]; break;
            case 4096:     if (n4096 < 3) p4096[n4096++] = d_in[i]; break;
            default: break;
        }
    }
    if (!px || !pw || !pfpw || !pii || !pfi || n4096 != 3) return;

    const float* x       = (const float*)px;
    const int*   wpacked = (const int*)pw;
    const float* wscale  = (const float*)p4096[0];
    const float* reduced = (const float*)p4096[1];
    const float* bias    = (const float*)p4096[2];
    const float* fpw     = (const float*)pfpw;
    const int*   int_idx = (const int*)pii;
    const int*   fp_idx  = (const int*)pfi;
    float*       out     = (float*)d_out;

    const size_t NEED = (size_t)67108864 + 32768;
    if (ws_size < NEED) return;

    char* ws = (char*)d_ws;
    __hip_bfloat16* Aq = (__hip_bfloat16*)ws;                            // 32 MiB
    __hip_bfloat16* Wb = (__hip_bfloat16*)(ws + (size_t)33554432);       // 32 MiB
    float* scale_ws    = (float*)(ws + (size_t)67108864);                // 16 KiB
    float* zero_ws     = (float*)(ws + (size_t)67108864 + 16384);        // 16 KiB

    prep_kernel<<<TOKENS + OUT_FEAT, 256, 0, stream>>>(
        x, int_idx, fp_idx, wpacked, fpw, wscale, Aq, Wb, scale_ws, zero_ws);
    gemm256<<<256, 512, 0, stream>>>(Aq, Wb, scale_ws, zero_ws,
                                     wscale, reduced, bias, out);
}

// Round 10
// 99.779 us; speedup vs baseline: 3.5002x; 1.4636x over previous
//
#include <hip/hip_runtime.h>
#include <hip/hip_bf16.h>

#define IN_FEAT 4096
#define OUT_FEAT 4096
#define FP_FEAT 256
#define INT_FEAT 3840
#define TOKENS 4096
#define PACKED_W (INT_FEAT / 2)  // 1920

#define NT_I8 60          // int K-tiles (K=64 i8 each)
#define NT_ALL 68         // + 8 fp sub-tiles (K=32 bf16 each)

typedef __attribute__((ext_vector_type(8))) short short8;
typedef __attribute__((ext_vector_type(4))) float f32x4;
typedef __attribute__((ext_vector_type(4))) int   int32x4;

// workspace layout (bytes)
#define AQ8_OFF   0u
#define WB8_OFF   16777216u
#define AFP_OFF   33554432u
#define WFP_OFF   35651584u
#define SCALE_OFF 37748736u
#define ZERO_OFF  37765120u
#define WS_NEED   37781504u

// ------------------------------------------------- fused quantize + unpack ---
// blocks 0..4095: quantize token row -> i8 q's + bf16 fp cols (x/sc).
// blocks 4096..8191: unpack weight row -> i8 w's + bf16 fp cols (w/ws).
__global__ __launch_bounds__(256) void prep_kernel(
    const float* __restrict__ x,
    const int* __restrict__ int_idx_raw,
    const int* __restrict__ fp_idx_raw,
    const int* __restrict__ wpacked_raw,
    const float* __restrict__ fpw,
    const float* __restrict__ wscale,
    signed char* __restrict__ Aq8,
    __hip_bfloat16* __restrict__ Afp,
    signed char* __restrict__ Wb8,
    __hip_bfloat16* __restrict__ Wfp,
    float* __restrict__ scale_ws,
    float* __restrict__ zero_ws)
{
    const int t = threadIdx.x;
    if (blockIdx.x < TOKENS) {
        const int m = blockIdx.x;
        const float* xr = x + (size_t)m * IN_FEAT;
        const bool is64 = (int_idx_raw[1] == 0) && (int_idx_raw[3] == 0);

        float v[15];
        float mn = 1e30f, mx = -1e30f;
#pragma unroll
        for (int j = 0; j < 15; ++j) {
            int k = t + j * 256;
            int idx = is64 ? int_idx_raw[2 * k] : int_idx_raw[k];
            float f = xr[idx];
            v[j] = f;
            mn = fminf(mn, f);
            mx = fmaxf(mx, f);
        }
#pragma unroll
        for (int off = 1; off < 64; off <<= 1) {
            mn = fminf(mn, __shfl_xor(mn, off));
            mx = fmaxf(mx, __shfl_xor(mx, off));
        }
        __shared__ float smn[4], smx[4];
        int wid = t >> 6, lane = t & 63;
        if (lane == 0) { smn[wid] = mn; smx[wid] = mx; }
        __syncthreads();
        if (t == 0) {
            float rmn = fminf(fminf(smn[0], smn[1]), fminf(smn[2], smn[3]));
            float rmx = fmaxf(fmaxf(smx[0], smx[1]), fmaxf(smx[2], smx[3]));
            float sc = fmaxf((rmx - rmn) / 15.0f, 1e-8f);
            smn[0] = rmn;
            smx[0] = sc;
            scale_ws[m] = sc;
            zero_ws[m] = rmn;
        }
        __syncthreads();
        const float zero = smn[0];
        const float sc = smx[0];

        signed char* ar = Aq8 + (size_t)m * INT_FEAT;
#pragma unroll
        for (int j = 0; j < 15; ++j) {
            int k = t + j * 256;
            float q = rintf((v[j] - zero) / sc) - 8.0f;  // IEEE div+rndne == np
            q = fminf(fmaxf(q, -8.0f), 7.0f);
            ar[k] = (signed char)(int)q;                 // exact small int
        }
        int fpi = is64 ? fp_idx_raw[2 * t] : fp_idx_raw[t];
        Afp[(size_t)m * FP_FEAT + t] = __float2bfloat16(xr[fpi] / sc);
    } else {
        const int n = blockIdx.x - TOKENS;
        bool is_i32 = true;
#pragma unroll
        for (int j = 0; j < 8; ++j) {
            unsigned w = (unsigned)wpacked_raw[j];
            if (w > 0xFFu) is_i32 = false;
        }
        short* wo = (short*)(Wb8 + (size_t)n * INT_FEAT);
#pragma unroll
        for (int j = 0; j < 8; ++j) {
            int k = t + j * 256;
            if (k < PACKED_W) {
                int p = is_i32 ? wpacked_raw[(size_t)n * PACKED_W + k]
                               : ((const unsigned char*)wpacked_raw)[(size_t)n * PACKED_W + k];
                int lo = p & 15; if (lo >= 8) lo -= 16;
                int hi = (p >> 4) & 15; if (hi >= 8) hi -= 16;
                wo[k] = (short)(((unsigned char)lo) | ((unsigned short)(unsigned char)hi << 8));
            }
        }
        float wsn = wscale[n];
        Wfp[(size_t)n * FP_FEAT + t] = __float2bfloat16(fpw[(size_t)n * FP_FEAT + t] / wsn);
    }
}

// --------------------------------------------- GEMM 256x256 i8 + bf16 tail ---
// 512 thr = 8 waves (2M x 4N), per-wave out 128x64. LDS = 3 buffers x 32KB
// (A 16KB + B 16KB each); tiles: 60 i8 (K=64) then 8 bf16 (K=32) -- both have
// 64B rows, shared addressing. Swizzle: row r, 16B chunk c holds k-chunk
// c ^ ((r>>1)&3); staging uses linear LDS dest + inverse-permuted global src
// (rule 21); reads XOR kg with (row>>1)&3 -> balanced 2/bank (free).
// Pipeline: per tile j: {12 ds_read_b128; stage(j+2) 4 gload_lds; 32 MFMA;
// vmcnt(4); bar}. Hazards: stage(j+1) landed for ALL waves because each
// wave's vmcnt(4) at end of j drains it, then the barrier; buf[(j+2)%3] =
// buf[(j-1)%3] whose reads retired (lgkm) before j-1's end-bar. vmcnt
// counted (4), never 0, except pipeline drain at j>=66.
// Numerics: int products exact in i32; cvt i32->f32 exact (<2^24); fp tail =
// same bf16 MFMA blocks in same order as r9 => absmax bit-exact 0.1992188.

__global__ __launch_bounds__(512, 2) void gemm256_i8(
    const signed char* __restrict__ Aq8,
    const __hip_bfloat16* __restrict__ Afp,
    const signed char* __restrict__ Wb8,
    const __hip_bfloat16* __restrict__ Wfp,
    const float* __restrict__ scale_ws,
    const float* __restrict__ zero_ws,
    const float* __restrict__ wscale,
    const float* __restrict__ reduced,
    const float* __restrict__ bias,
    float* __restrict__ out)
{
    __shared__ __align__(16) char lds[98304];  // 96 KiB = 3 x (16K A + 16K B)

    const int t = threadIdx.x;
    const int lane = t & 63, wid = t >> 6;
    const int wr = wid >> 2;                   // 0..1
    const int wc = wid & 3;                    // 0..3
    const int r16 = lane & 15;
    const int kg = lane >> 4;                  // 0..3

    // XCD-aware block swizzle (256 blocks, 8 XCDs)
    const int bid = blockIdx.x;
    const int sb = (bid & 7) * 32 + (bid >> 3);
    const int tileM = (sb >> 4) * 256;
    const int tileN = (sb & 15) * 256;

    // staging geometry: 1024 16B-chunks per operand tile, 2 per thread
    const int id0 = t, id1 = 512 + t;
    const int r0 = id0 >> 2, c0 = id0 & 3;
    const int r1 = id1 >> 2, c1 = id1 & 3;
    const int sw0 = ((c0 ^ ((r0 >> 1) & 3)) << 4);   // byte in 64B row
    const int sw1 = ((c1 ^ ((r1 >> 1) & 3)) << 4);
    const char* a8_0 = (const char*)Aq8 + (size_t)(tileM + r0) * INT_FEAT + sw0;
    const char* a8_1 = (const char*)Aq8 + (size_t)(tileM + r1) * INT_FEAT + sw1;
    const char* b8_0 = (const char*)Wb8 + (size_t)(tileN + r0) * INT_FEAT + sw0;
    const char* b8_1 = (const char*)Wb8 + (size_t)(tileN + r1) * INT_FEAT + sw1;
    const char* af_0 = (const char*)Afp + (size_t)(tileM + r0) * 512 + sw0;
    const char* af_1 = (const char*)Afp + (size_t)(tileM + r1) * 512 + sw1;
    const char* bf_0 = (const char*)Wfp + (size_t)(tileN + r0) * 512 + sw0;
    const char* bf_1 = (const char*)Wfp + (size_t)(tileN + r1) * 512 + sw1;
    const int dst0 = id0 << 4, dst1 = id1 << 4;      // linear LDS byte dests

    auto stage = [&](int vt, int bufB) {
        const char *pa0, *pa1, *pb0, *pb1;
        if (vt < NT_I8) {
            int ko = vt * 64;
            pa0 = a8_0 + ko; pa1 = a8_1 + ko; pb0 = b8_0 + ko; pb1 = b8_1 + ko;
        } else {
            int ko = (vt - NT_I8) * 64;
            pa0 = af_0 + ko; pa1 = af_1 + ko; pb0 = bf_0 + ko; pb1 = bf_1 + ko;
        }
        __builtin_amdgcn_global_load_lds(
            (const __attribute__((address_space(1))) void*)pa0,
            (__attribute__((address_space(3))) void*)(lds + bufB + dst0), 16, 0, 0);
        __builtin_amdgcn_global_load_lds(
            (const __attribute__((address_space(1))) void*)pa1,
            (__attribute__((address_space(3))) void*)(lds + bufB + dst1), 16, 0, 0);
        __builtin_amdgcn_global_load_lds(
            (const __attribute__((address_space(1))) void*)pb0,
            (__attribute__((address_space(3))) void*)(lds + bufB + 16384 + dst0), 16, 0, 0);
        __builtin_amdgcn_global_load_lds(
            (const __attribute__((address_space(1))) void*)pb1,
            (__attribute__((address_space(3))) void*)(lds + bufB + 16384 + dst1), 16, 0, 0);
    };

    // fragment read byte-offsets (independent of dtype: 64B rows, 16B frags)
    int aOff[8], bOff[4];
#pragma unroll
    for (int mf = 0; mf < 8; ++mf) {
        int ra = wr * 128 + mf * 16 + r16;
        aOff[mf] = ra * 64 + ((((ra >> 1) & 3) ^ kg) << 4);
    }
#pragma unroll
    for (int nf = 0; nf < 4; ++nf) {
        int rb = wc * 64 + nf * 16 + r16;
        bOff[nf] = 16384 + rb * 64 + ((((rb >> 1) & 3) ^ kg) << 4);
    }

    f32x4 acc[8][4];
#pragma unroll
    for (int mf = 0; mf < 8; ++mf)
#pragma unroll
        for (int nf = 0; nf < 4; ++nf)
            acc[mf][nf] = (f32x4){0.f, 0.f, 0.f, 0.f};  // int32 0 bit-identical

    // prologue: stage tiles 0,1; drain tile 0 (vmcnt 4 leaves tile1 in flight)
    stage(0, 0);
    stage(1, 32768);
    asm volatile("s_waitcnt vmcnt(4)" ::: "memory");
    __builtin_amdgcn_sched_barrier(0);
    __builtin_amdgcn_s_barrier();
    __builtin_amdgcn_sched_barrier(0);

    int bufB = 0;
    // ---- loop 1: 60 i8 K-tiles (exact integer accumulation) ----
    for (int vt = 0; vt < NT_I8; ++vt) {
        int32x4 aI[8], bI[4];
#pragma unroll
        for (int mf = 0; mf < 8; ++mf)
            aI[mf] = *(const int32x4*)(lds + bufB + aOff[mf]);
#pragma unroll
        for (int nf = 0; nf < 4; ++nf)
            bI[nf] = *(const int32x4*)(lds + bufB + bOff[nf]);

        int buf2B = (bufB == 0) ? 65536 : bufB - 32768;   // (vt+2)%3
        stage(vt + 2, buf2B);

        __builtin_amdgcn_s_setprio(1);
#pragma unroll
        for (int mf = 0; mf < 8; ++mf)
#pragma unroll
            for (int nf = 0; nf < 4; ++nf)
                acc[mf][nf] = __builtin_bit_cast(f32x4,
                    __builtin_amdgcn_mfma_i32_16x16x64_i8(
                        aI[mf], bI[nf],
                        __builtin_bit_cast(int32x4, acc[mf][nf]), 0, 0, 0));
        __builtin_amdgcn_s_setprio(0);

        asm volatile("s_waitcnt vmcnt(4)" ::: "memory");
        __builtin_amdgcn_sched_barrier(0);
        __builtin_amdgcn_s_barrier();
        __builtin_amdgcn_sched_barrier(0);
        bufB = (bufB == 65536) ? 0 : bufB + 32768;
    }

    // ---- exact int32 -> f32 conversion (in place) ----
#pragma unroll
    for (int mf = 0; mf < 8; ++mf)
#pragma unroll
        for (int nf = 0; nf < 4; ++nf) {
            int32x4 vi = __builtin_bit_cast(int32x4, acc[mf][nf]);
            f32x4 vf;
#pragma unroll
            for (int i = 0; i < 4; ++i) vf[i] = (float)vi[i];
            acc[mf][nf] = vf;
        }

    // ---- loop 2: 8 bf16 fp sub-tiles (K=32 each) ----
    for (int vt = NT_I8; vt < NT_ALL; ++vt) {
        short8 aF[8], bF[4];
#pragma unroll
        for (int mf = 0; mf < 8; ++mf)
            aF[mf] = *(const short8*)(lds + bufB + aOff[mf]);
#pragma unroll
        for (int nf = 0; nf < 4; ++nf)
            bF[nf] = *(const short8*)(lds + bufB + bOff[nf]);

        if (vt + 2 < NT_ALL) {
            int buf2B = (bufB == 0) ? 65536 : bufB - 32768;
            stage(vt + 2, buf2B);
        }

        __builtin_amdgcn_s_setprio(1);
#pragma unroll
        for (int mf = 0; mf < 8; ++mf)
#pragma unroll
            for (int nf = 0; nf < 4; ++nf)
                acc[mf][nf] = __builtin_amdgcn_mfma_f32_16x16x32_bf16(
                    aF[mf], bF[nf], acc[mf][nf], 0, 0, 0);
        __builtin_amdgcn_s_setprio(0);

        if (vt + 2 < NT_ALL)
            asm volatile("s_waitcnt vmcnt(4)" ::: "memory");
        else
            asm volatile("s_waitcnt vmcnt(0)" ::: "memory");
        __builtin_amdgcn_sched_barrier(0);
        __builtin_amdgcn_s_barrier();
        __builtin_amdgcn_sched_barrier(0);
        bufB = (bufB == 65536) ? 0 : bufB + 32768;
    }

    // epilogue: out = sc*ws*acc + (zero + 8*sc)*reduced + bias
    const int cr4 = kg * 4;
#pragma unroll
    for (int mf = 0; mf < 8; ++mf) {
#pragma unroll
        for (int nf = 0; nf < 4; ++nf) {
            int n = tileN + wc * 64 + nf * 16 + r16;
            float ws = wscale[n];
            float rd = reduced[n];
            float bs = bias[n];
#pragma unroll
            for (int i = 0; i < 4; ++i) {
                int m = tileM + wr * 128 + mf * 16 + cr4 + i;
                float sc = scale_ws[m];
                float zr = zero_ws[m];
                out[(size_t)m * OUT_FEAT + n] =
                    sc * ws * acc[mf][nf][i]
                    + (zr + sc * 8.0f) * rd + bs;
            }
        }
    }
}

// ------------------------------------------------------------------ launch ---
extern "C" void kernel_launch(void* const* d_in, const int* in_sizes, int n_in,
                              void* d_out, int out_size, void* d_ws, size_t ws_size,
                              hipStream_t stream)
{
    const void* px = 0; const void* pw = 0; const void* pfpw = 0;
    const void* pii = 0; const void* pfi = 0;
    const void* p4096[3] = {0, 0, 0}; int n4096 = 0;
    for (int i = 0; i < n_in; ++i) {
        switch (in_sizes[i]) {
            case 16777216: px = d_in[i]; break;
            case 7864320:  pw = d_in[i]; break;
            case 1048576:  pfpw = d_in[i]; break;
            case 3840:     pii = d_in[i]; break;
            case 256:      pfi = d_in[i]; break;
            case 4096:     if (n4096 < 3) p4096[n4096++] = d_in[i]; break;
            default: break;
        }
    }
    if (!px || !pw || !pfpw || !pii || !pfi || n4096 != 3) return;

    const float* x       = (const float*)px;
    const int*   wpacked = (const int*)pw;
    const float* wscale  = (const float*)p4096[0];
    const float* reduced = (const float*)p4096[1];
    const float* bias    = (const float*)p4096[2];
    const float* fpw     = (const float*)pfpw;
    const int*   int_idx = (const int*)pii;
    const int*   fp_idx  = (const int*)pfi;
    float*       out     = (float*)d_out;

    if (ws_size < (size_t)WS_NEED) return;

    char* ws = (char*)d_ws;
    signed char*    Aq8 = (signed char*)(ws + AQ8_OFF);
    signed char*    Wb8 = (signed char*)(ws + WB8_OFF);
    __hip_bfloat16* Afp = (__hip_bfloat16*)(ws + AFP_OFF);
    __hip_bfloat16* Wfp = (__hip_bfloat16*)(ws + WFP_OFF);
    float* scale_ws     = (float*)(ws + SCALE_OFF);
    float* zero_ws      = (float*)(ws + ZERO_OFF);

    prep_kernel<<<TOKENS + OUT_FEAT, 256, 0, stream>>>(
        x, int_idx, fp_idx, wpacked, fpw, wscale,
        Aq8, Afp, Wb8, Wfp, scale_ws, zero_ws);
    gemm256_i8<<<256, 512, 0, stream>>>(Aq8, Afp, Wb8, Wfp,
                                        scale_ws, zero_ws,
                                        wscale, reduced, bias, out);
}

// Round 11
// 99.197 us; speedup vs baseline: 3.5207x; 1.0059x over previous
//
#include <hip/hip_runtime.h>
#include <hip/hip_bf16.h>

#define IN_FEAT 4096
#define OUT_FEAT 4096
#define FP_FEAT 256
#define INT_FEAT 3840
#define TOKENS 4096
#define PACKED_W (INT_FEAT / 2)  // 1920

#define NT_I8 60          // int K-tiles (K=64 i8 each)
#define NT_ALL 68         // + 8 fp sub-tiles (K=32 bf16 each)

typedef __attribute__((ext_vector_type(8))) short short8;
typedef __attribute__((ext_vector_type(4))) float f32x4;
typedef __attribute__((ext_vector_type(4))) int   int32x4;

// workspace layout (bytes)
#define AQ8_OFF   0u
#define WB8_OFF   16777216u
#define AFP_OFF   33554432u
#define WFP_OFF   35651584u
#define SCALE_OFF 37748736u
#define ZERO_OFF  37765120u
#define WS_NEED   37781504u

// ------------------------------------------------- fused quantize + unpack ---
__global__ __launch_bounds__(256) void prep_kernel(
    const float* __restrict__ x,
    const int* __restrict__ int_idx_raw,
    const int* __restrict__ fp_idx_raw,
    const int* __restrict__ wpacked_raw,
    const float* __restrict__ fpw,
    const float* __restrict__ wscale,
    signed char* __restrict__ Aq8,
    __hip_bfloat16* __restrict__ Afp,
    signed char* __restrict__ Wb8,
    __hip_bfloat16* __restrict__ Wfp,
    float* __restrict__ scale_ws,
    float* __restrict__ zero_ws)
{
    const int t = threadIdx.x;
    if (blockIdx.x < TOKENS) {
        const int m = blockIdx.x;
        const float* xr = x + (size_t)m * IN_FEAT;
        const bool is64 = (int_idx_raw[1] == 0) && (int_idx_raw[3] == 0);

        float v[15];
        float mn = 1e30f, mx = -1e30f;
#pragma unroll
        for (int j = 0; j < 15; ++j) {
            int k = t + j * 256;
            int idx = is64 ? int_idx_raw[2 * k] : int_idx_raw[k];
            float f = xr[idx];
            v[j] = f;
            mn = fminf(mn, f);
            mx = fmaxf(mx, f);
        }
#pragma unroll
        for (int off = 1; off < 64; off <<= 1) {
            mn = fminf(mn, __shfl_xor(mn, off));
            mx = fmaxf(mx, __shfl_xor(mx, off));
        }
        __shared__ float smn[4], smx[4];
        int wid = t >> 6, lane = t & 63;
        if (lane == 0) { smn[wid] = mn; smx[wid] = mx; }
        __syncthreads();
        if (t == 0) {
            float rmn = fminf(fminf(smn[0], smn[1]), fminf(smn[2], smn[3]));
            float rmx = fmaxf(fmaxf(smx[0], smx[1]), fmaxf(smx[2], smx[3]));
            float sc = fmaxf((rmx - rmn) / 15.0f, 1e-8f);
            smn[0] = rmn;
            smx[0] = sc;
            scale_ws[m] = sc;
            zero_ws[m] = rmn;
        }
        __syncthreads();
        const float zero = smn[0];
        const float sc = smx[0];

        signed char* ar = Aq8 + (size_t)m * INT_FEAT;
#pragma unroll
        for (int j = 0; j < 15; ++j) {
            int k = t + j * 256;
            float q = rintf((v[j] - zero) / sc) - 8.0f;  // IEEE div+rndne == np
            q = fminf(fmaxf(q, -8.0f), 7.0f);
            ar[k] = (signed char)(int)q;                 // exact small int
        }
        int fpi = is64 ? fp_idx_raw[2 * t] : fp_idx_raw[t];
        Afp[(size_t)m * FP_FEAT + t] = __float2bfloat16(xr[fpi] / sc);
    } else {
        const int n = blockIdx.x - TOKENS;
        bool is_i32 = true;
#pragma unroll
        for (int j = 0; j < 8; ++j) {
            unsigned w = (unsigned)wpacked_raw[j];
            if (w > 0xFFu) is_i32 = false;
        }
        short* wo = (short*)(Wb8 + (size_t)n * INT_FEAT);
#pragma unroll
        for (int j = 0; j < 8; ++j) {
            int k = t + j * 256;
            if (k < PACKED_W) {
                int p = is_i32 ? wpacked_raw[(size_t)n * PACKED_W + k]
                               : ((const unsigned char*)wpacked_raw)[(size_t)n * PACKED_W + k];
                int lo = p & 15; if (lo >= 8) lo -= 16;
                int hi = (p >> 4) & 15; if (hi >= 8) hi -= 16;
                wo[k] = (short)(((unsigned char)lo) | ((unsigned short)(unsigned char)hi << 8));
            }
        }
        float wsn = wscale[n];
        Wfp[(size_t)n * FP_FEAT + t] = __float2bfloat16(fpw[(size_t)n * FP_FEAT + t] / wsn);
    }
}

// --------------------------------------------- GEMM 256x256 i8 + bf16 tail ---
// 512 thr = 8 waves (2M x 4N), per-wave out 128x64. LDS = 4 buffers x 32KB
// (deep pipeline: stage vt+3 at tile vt; end-of-tile vmcnt(8) drains exactly
// stage(vt+1), keeps vt+2/vt+3 in flight -- 3-tile prefetch distance covers
// L2/HBM latency; never drains to 0 in steady state).
// Swizzle (verified r10, 0 conflicts): row r, 16B chunk c holds k-chunk
// c ^ ((r>>1)&3); linear gload_lds dest + inverse-permuted global src.
// Hazards: buf[(vt+3)&3] == buf[(vt-1)&3], whose reads retired (lgkm before
// MFMA) before tile vt-1's end barrier; stage issued after that barrier.
// Reads of buf[vt&3] protected by prev tile's vmcnt(8)+barrier.
// Numerics: K-order per acc identical to r10 -> absmax bit-exact 0.1992188.

__global__ __launch_bounds__(512, 2) void gemm256_i8(
    const signed char* __restrict__ Aq8,
    const __hip_bfloat16* __restrict__ Afp,
    const signed char* __restrict__ Wb8,
    const __hip_bfloat16* __restrict__ Wfp,
    const float* __restrict__ scale_ws,
    const float* __restrict__ zero_ws,
    const float* __restrict__ wscale,
    const float* __restrict__ reduced,
    const float* __restrict__ bias,
    float* __restrict__ out)
{
    __shared__ __align__(16) char lds[131072];  // 128 KiB = 4 x (16K A + 16K B)

    const int t = threadIdx.x;
    const int lane = t & 63, wid = t >> 6;
    const int wr = wid >> 2;                   // 0..1
    const int wc = wid & 3;                    // 0..3
    const int r16 = lane & 15;
    const int kg = lane >> 4;                  // 0..3

    // XCD-aware block swizzle (256 blocks, 8 XCDs)
    const int bid = blockIdx.x;
    const int sb = (bid & 7) * 32 + (bid >> 3);
    const int tileM = (sb >> 4) * 256;
    const int tileN = (sb & 15) * 256;

    // staging geometry: 1024 16B-chunks per operand tile, 2 per thread
    const int id0 = t, id1 = 512 + t;
    const int r0 = id0 >> 2, c0 = id0 & 3;
    const int r1 = id1 >> 2, c1 = id1 & 3;
    const int sw0 = ((c0 ^ ((r0 >> 1) & 3)) << 4);
    const int sw1 = ((c1 ^ ((r1 >> 1) & 3)) << 4);
    const char* a8_0 = (const char*)Aq8 + (size_t)(tileM + r0) * INT_FEAT + sw0;
    const char* a8_1 = (const char*)Aq8 + (size_t)(tileM + r1) * INT_FEAT + sw1;
    const char* b8_0 = (const char*)Wb8 + (size_t)(tileN + r0) * INT_FEAT + sw0;
    const char* b8_1 = (const char*)Wb8 + (size_t)(tileN + r1) * INT_FEAT + sw1;
    const char* af_0 = (const char*)Afp + (size_t)(tileM + r0) * 512 + sw0;
    const char* af_1 = (const char*)Afp + (size_t)(tileM + r1) * 512 + sw1;
    const char* bf_0 = (const char*)Wfp + (size_t)(tileN + r0) * 512 + sw0;
    const char* bf_1 = (const char*)Wfp + (size_t)(tileN + r1) * 512 + sw1;
    const int dst0 = id0 << 4, dst1 = id1 << 4;

    auto stage = [&](int vt, int bufB) {
        const char *pa0, *pa1, *pb0, *pb1;
        if (vt < NT_I8) {
            int ko = vt * 64;
            pa0 = a8_0 + ko; pa1 = a8_1 + ko; pb0 = b8_0 + ko; pb1 = b8_1 + ko;
        } else {
            int ko = (vt - NT_I8) * 64;
            pa0 = af_0 + ko; pa1 = af_1 + ko; pb0 = bf_0 + ko; pb1 = bf_1 + ko;
        }
        __builtin_amdgcn_global_load_lds(
            (const __attribute__((address_space(1))) void*)pa0,
            (__attribute__((address_space(3))) void*)(lds + bufB + dst0), 16, 0, 0);
        __builtin_amdgcn_global_load_lds(
            (const __attribute__((address_space(1))) void*)pa1,
            (__attribute__((address_space(3))) void*)(lds + bufB + dst1), 16, 0, 0);
        __builtin_amdgcn_global_load_lds(
            (const __attribute__((address_space(1))) void*)pb0,
            (__attribute__((address_space(3))) void*)(lds + bufB + 16384 + dst0), 16, 0, 0);
        __builtin_amdgcn_global_load_lds(
            (const __attribute__((address_space(1))) void*)pb1,
            (__attribute__((address_space(3))) void*)(lds + bufB + 16384 + dst1), 16, 0, 0);
    };

    // fragment read byte-offsets (dtype-independent: 64B rows, 16B frags)
    int aOff[8], bOff[4];
#pragma unroll
    for (int mf = 0; mf < 8; ++mf) {
        int ra = wr * 128 + mf * 16 + r16;
        aOff[mf] = ra * 64 + ((((ra >> 1) & 3) ^ kg) << 4);
    }
#pragma unroll
    for (int nf = 0; nf < 4; ++nf) {
        int rb = wc * 64 + nf * 16 + r16;
        bOff[nf] = 16384 + rb * 64 + ((((rb >> 1) & 3) ^ kg) << 4);
    }

    f32x4 acc[8][4];
#pragma unroll
    for (int mf = 0; mf < 8; ++mf)
#pragma unroll
        for (int nf = 0; nf < 4; ++nf)
            acc[mf][nf] = (f32x4){0.f, 0.f, 0.f, 0.f};

    // prologue: stage tiles 0,1,2; drain tile 0 (vmcnt(8) leaves 1,2 flying)
    stage(0, 0);
    stage(1, 32768);
    stage(2, 65536);
    asm volatile("s_waitcnt vmcnt(8)" ::: "memory");
    __builtin_amdgcn_sched_barrier(0);
    __builtin_amdgcn_s_barrier();
    __builtin_amdgcn_sched_barrier(0);

    // ---- loop 1: 60 i8 K-tiles (exact integer accumulation) ----
    for (int vt = 0; vt < NT_I8; ++vt) {
        const int bufB = (vt & 3) << 15;
        int32x4 aI[8], bI[4];
#pragma unroll
        for (int mf = 0; mf < 8; ++mf)
            aI[mf] = *(const int32x4*)(lds + bufB + aOff[mf]);
#pragma unroll
        for (int nf = 0; nf < 4; ++nf)
            bI[nf] = *(const int32x4*)(lds + bufB + bOff[nf]);

        stage(vt + 3, ((vt + 3) & 3) << 15);   // vt+3 <= 62 < NT_ALL always

        __builtin_amdgcn_s_setprio(1);
#pragma unroll
        for (int mf = 0; mf < 8; ++mf)
#pragma unroll
            for (int nf = 0; nf < 4; ++nf)
                acc[mf][nf] = __builtin_bit_cast(f32x4,
                    __builtin_amdgcn_mfma_i32_16x16x64_i8(
                        aI[mf], bI[nf],
                        __builtin_bit_cast(int32x4, acc[mf][nf]), 0, 0, 0));
        __builtin_amdgcn_s_setprio(0);

        asm volatile("s_waitcnt vmcnt(8)" ::: "memory");
        __builtin_amdgcn_sched_barrier(0);
        __builtin_amdgcn_s_barrier();
        __builtin_amdgcn_sched_barrier(0);
    }

    // ---- exact int32 -> f32 conversion (in place) ----
#pragma unroll
    for (int mf = 0; mf < 8; ++mf)
#pragma unroll
        for (int nf = 0; nf < 4; ++nf) {
            int32x4 vi = __builtin_bit_cast(int32x4, acc[mf][nf]);
            f32x4 vf;
#pragma unroll
            for (int i = 0; i < 4; ++i) vf[i] = (float)vi[i];
            acc[mf][nf] = vf;
        }

    // ---- loop 2: 8 bf16 fp sub-tiles (K=32 each) ----
    for (int vt = NT_I8; vt < NT_ALL; ++vt) {
        const int bufB = (vt & 3) << 15;
        short8 aF[8], bF[4];
#pragma unroll
        for (int mf = 0; mf < 8; ++mf)
            aF[mf] = *(const short8*)(lds + bufB + aOff[mf]);
#pragma unroll
        for (int nf = 0; nf < 4; ++nf)
            bF[nf] = *(const short8*)(lds + bufB + bOff[nf]);

        if (vt + 3 < NT_ALL)
            stage(vt + 3, ((vt + 3) & 3) << 15);

        __builtin_amdgcn_s_setprio(1);
#pragma unroll
        for (int mf = 0; mf < 8; ++mf)
#pragma unroll
            for (int nf = 0; nf < 4; ++nf)
                acc[mf][nf] = __builtin_amdgcn_mfma_f32_16x16x32_bf16(
                    aF[mf], bF[nf], acc[mf][nf], 0, 0, 0);
        __builtin_amdgcn_s_setprio(0);

        // outstanding stages: u in [vt+1, min(vt+3, 67)]; drain stage(vt+1)
        if (vt <= NT_ALL - 4)
            asm volatile("s_waitcnt vmcnt(8)" ::: "memory");
        else if (vt == NT_ALL - 3)
            asm volatile("s_waitcnt vmcnt(4)" ::: "memory");
        else if (vt == NT_ALL - 2)
            asm volatile("s_waitcnt vmcnt(0)" ::: "memory");
        __builtin_amdgcn_sched_barrier(0);
        __builtin_amdgcn_s_barrier();
        __builtin_amdgcn_sched_barrier(0);
    }

    // epilogue: out = sc*ws*acc + (zero + 8*sc)*reduced + bias
    const int cr4 = kg * 4;
#pragma unroll
    for (int mf = 0; mf < 8; ++mf) {
#pragma unroll
        for (int nf = 0; nf < 4; ++nf) {
            int n = tileN + wc * 64 + nf * 16 + r16;
            float ws = wscale[n];
            float rd = reduced[n];
            float bs = bias[n];
#pragma unroll
            for (int i = 0; i < 4; ++i) {
                int m = tileM + wr * 128 + mf * 16 + cr4 + i;
                float sc = scale_ws[m];
                float zr = zero_ws[m];
                out[(size_t)m * OUT_FEAT + n] =
                    sc * ws * acc[mf][nf][i]
                    + (zr + sc * 8.0f) * rd + bs;
            }
        }
    }
}

// ------------------------------------------------------------------ launch ---
extern "C" void kernel_launch(void* const* d_in, const int* in_sizes, int n_in,
                              void* d_out, int out_size, void* d_ws, size_t ws_size,
                              hipStream_t stream)
{
    const void* px = 0; const void* pw = 0; const void* pfpw = 0;
    const void* pii = 0; const void* pfi = 0;
    const void* p4096[3] = {0, 0, 0}; int n4096 = 0;
    for (int i = 0; i < n_in; ++i) {
        switch (in_sizes[i]) {
            case 16777216: px = d_in[i]; break;
            case 7864320:  pw = d_in[i]; break;
            case 1048576:  pfpw = d_in[i]; break;
            case 3840:     pii = d_in[i]; break;
            case 256:      pfi = d_in[i]; break;
            case 4096:     if (n4096 < 3) p4096[n4096++] = d_in[i]; break;
            default: break;
        }
    }
    if (!px || !pw || !pfpw || !pii || !pfi || n4096 != 3) return;

    const float* x       = (const float*)px;
    const int*   wpacked = (const int*)pw;
    const float* wscale  = (const float*)p4096[0];
    const float* reduced = (const float*)p4096[1];
    const float* bias    = (const float*)p4096[2];
    const float* fpw     = (const float*)pfpw;
    const int*   int_idx = (const int*)pii;
    const int*   fp_idx  = (const int*)pfi;
    float*       out     = (float*)d_out;

    if (ws_size < (size_t)WS_NEED) return;

    char* ws = (char*)d_ws;
    signed char*    Aq8 = (signed char*)(ws + AQ8_OFF);
    signed char*    Wb8 = (signed char*)(ws + WB8_OFF);
    __hip_bfloat16* Afp = (__hip_bfloat16*)(ws + AFP_OFF);
    __hip_bfloat16* Wfp = (__hip_bfloat16*)(ws + WFP_OFF);
    float* scale_ws     = (float*)(ws + SCALE_OFF);
    float* zero_ws      = (float*)(ws + ZERO_OFF);

    prep_kernel<<<TOKENS + OUT_FEAT, 256, 0, stream>>>(
        x, int_idx, fp_idx, wpacked, fpw, wscale,
        Aq8, Afp, Wb8, Wfp, scale_ws, zero_ws);
    gemm256_i8<<<256, 512, 0, stream>>>(Aq8, Afp, Wb8, Wfp,
                                        scale_ws, zero_ws,
                                        wscale, reduced, bias, out);
}

// Round 12
// 98.711 us; speedup vs baseline: 3.5381x; 1.0049x over previous
//
#include <hip/hip_runtime.h>
#include <hip/hip_bf16.h>

#define IN_FEAT 4096
#define OUT_FEAT 4096
#define FP_FEAT 256
#define INT_FEAT 3840
#define TOKENS 4096
#define PACKED_W (INT_FEAT / 2)  // 1920

#define NT_I8 60          // int K-tiles (K=64 i8 each)
#define NT_ALL 68         // + 8 fp sub-tiles (K=32 bf16 each)

typedef __attribute__((ext_vector_type(8))) short short8;
typedef __attribute__((ext_vector_type(4))) float f32x4;
typedef __attribute__((ext_vector_type(4))) int   int32x4;

// workspace layout (bytes)
#define AQ8_OFF   0u
#define WB8_OFF   16777216u
#define AFP_OFF   33554432u
#define WFP_OFF   35651584u
#define SCALE_OFF 37748736u
#define ZERO_OFF  37765120u
#define WS_NEED   37781504u

// ------------------------------------------------- fused quantize + unpack ---
__global__ __launch_bounds__(256) void prep_kernel(
    const float* __restrict__ x,
    const int* __restrict__ int_idx_raw,
    const int* __restrict__ fp_idx_raw,
    const int* __restrict__ wpacked_raw,
    const float* __restrict__ fpw,
    const float* __restrict__ wscale,
    signed char* __restrict__ Aq8,
    __hip_bfloat16* __restrict__ Afp,
    signed char* __restrict__ Wb8,
    __hip_bfloat16* __restrict__ Wfp,
    float* __restrict__ scale_ws,
    float* __restrict__ zero_ws)
{
    const int t = threadIdx.x;
    if (blockIdx.x < TOKENS) {
        const int m = blockIdx.x;
        const float* xr = x + (size_t)m * IN_FEAT;
        const bool is64 = (int_idx_raw[1] == 0) && (int_idx_raw[3] == 0);

        float v[15];
        float mn = 1e30f, mx = -1e30f;
#pragma unroll
        for (int j = 0; j < 15; ++j) {
            int k = t + j * 256;
            int idx = is64 ? int_idx_raw[2 * k] : int_idx_raw[k];
            float f = xr[idx];
            v[j] = f;
            mn = fminf(mn, f);
            mx = fmaxf(mx, f);
        }
#pragma unroll
        for (int off = 1; off < 64; off <<= 1) {
            mn = fminf(mn, __shfl_xor(mn, off));
            mx = fmaxf(mx, __shfl_xor(mx, off));
        }
        __shared__ float smn[4], smx[4];
        int wid = t >> 6, lane = t & 63;
        if (lane == 0) { smn[wid] = mn; smx[wid] = mx; }
        __syncthreads();
        if (t == 0) {
            float rmn = fminf(fminf(smn[0], smn[1]), fminf(smn[2], smn[3]));
            float rmx = fmaxf(fmaxf(smx[0], smx[1]), fmaxf(smx[2], smx[3]));
            float sc = fmaxf((rmx - rmn) / 15.0f, 1e-8f);
            smn[0] = rmn;
            smx[0] = sc;
            scale_ws[m] = sc;
            zero_ws[m] = rmn;
        }
        __syncthreads();
        const float zero = smn[0];
        const float sc = smx[0];

        signed char* ar = Aq8 + (size_t)m * INT_FEAT;
#pragma unroll
        for (int j = 0; j < 15; ++j) {
            int k = t + j * 256;
            float q = rintf((v[j] - zero) / sc) - 8.0f;  // IEEE div+rndne == np
            q = fminf(fmaxf(q, -8.0f), 7.0f);
            ar[k] = (signed char)(int)q;                 // exact small int
        }
        int fpi = is64 ? fp_idx_raw[2 * t] : fp_idx_raw[t];
        Afp[(size_t)m * FP_FEAT + t] = __float2bfloat16(xr[fpi] / sc);
    } else {
        const int n = blockIdx.x - TOKENS;
        bool is_i32 = true;
#pragma unroll
        for (int j = 0; j < 8; ++j) {
            unsigned w = (unsigned)wpacked_raw[j];
            if (w > 0xFFu) is_i32 = false;
        }
        short* wo = (short*)(Wb8 + (size_t)n * INT_FEAT);
#pragma unroll
        for (int j = 0; j < 8; ++j) {
            int k = t + j * 256;
            if (k < PACKED_W) {
                int p = is_i32 ? wpacked_raw[(size_t)n * PACKED_W + k]
                               : ((const unsigned char*)wpacked_raw)[(size_t)n * PACKED_W + k];
                int lo = p & 15; if (lo >= 8) lo -= 16;
                int hi = (p >> 4) & 15; if (hi >= 8) hi -= 16;
                wo[k] = (short)(((unsigned char)lo) | ((unsigned short)(unsigned char)hi << 8));
            }
        }
        float wsn = wscale[n];
        Wfp[(size_t)n * FP_FEAT + t] = __float2bfloat16(fpw[(size_t)n * FP_FEAT + t] / wsn);
    }
}

// --------------------------------------------- GEMM 256x256 i8 + bf16 tail ---
// Identical sync/vmcnt structure to r11 (4 x 32KB buffers, stage vt+3,
// vmcnt(8) counted drain, 1 barrier/tile, 0 bank conflicts).
// r12 micro-fixes (register-neutral):
//  * B fragments read BEFORE A: first MFMA (a0*b0) waits on the 5th read,
//    each a_mf read (~12cyc apart) unlocks 4 MFMAs -> matrix pipe fills
//    during the read phase (compiler emits fine-grained lgkmcnt).
//  * native int32x4 accumulator in the i8 loop (no per-MFMA bit_casts).

__global__ __launch_bounds__(512, 2) void gemm256_i8(
    const signed char* __restrict__ Aq8,
    const __hip_bfloat16* __restrict__ Afp,
    const signed char* __restrict__ Wb8,
    const __hip_bfloat16* __restrict__ Wfp,
    const float* __restrict__ scale_ws,
    const float* __restrict__ zero_ws,
    const float* __restrict__ wscale,
    const float* __restrict__ reduced,
    const float* __restrict__ bias,
    float* __restrict__ out)
{
    __shared__ __align__(16) char lds[131072];  // 128 KiB = 4 x (16K A + 16K B)

    const int t = threadIdx.x;
    const int lane = t & 63, wid = t >> 6;
    const int wr = wid >> 2;                   // 0..1
    const int wc = wid & 3;                    // 0..3
    const int r16 = lane & 15;
    const int kg = lane >> 4;                  // 0..3

    // XCD-aware block swizzle (256 blocks, 8 XCDs)
    const int bid = blockIdx.x;
    const int sb = (bid & 7) * 32 + (bid >> 3);
    const int tileM = (sb >> 4) * 256;
    const int tileN = (sb & 15) * 256;

    // staging geometry: 1024 16B-chunks per operand tile, 2 per thread
    const int id0 = t, id1 = 512 + t;
    const int r0 = id0 >> 2, c0 = id0 & 3;
    const int r1 = id1 >> 2, c1 = id1 & 3;
    const int sw0 = ((c0 ^ ((r0 >> 1) & 3)) << 4);
    const int sw1 = ((c1 ^ ((r1 >> 1) & 3)) << 4);
    const char* a8_0 = (const char*)Aq8 + (size_t)(tileM + r0) * INT_FEAT + sw0;
    const char* a8_1 = (const char*)Aq8 + (size_t)(tileM + r1) * INT_FEAT + sw1;
    const char* b8_0 = (const char*)Wb8 + (size_t)(tileN + r0) * INT_FEAT + sw0;
    const char* b8_1 = (const char*)Wb8 + (size_t)(tileN + r1) * INT_FEAT + sw1;
    const char* af_0 = (const char*)Afp + (size_t)(tileM + r0) * 512 + sw0;
    const char* af_1 = (const char*)Afp + (size_t)(tileM + r1) * 512 + sw1;
    const char* bf_0 = (const char*)Wfp + (size_t)(tileN + r0) * 512 + sw0;
    const char* bf_1 = (const char*)Wfp + (size_t)(tileN + r1) * 512 + sw1;
    const int dst0 = id0 << 4, dst1 = id1 << 4;

    auto stage = [&](int vt, int bufB) {
        const char *pa0, *pa1, *pb0, *pb1;
        if (vt < NT_I8) {
            int ko = vt * 64;
            pa0 = a8_0 + ko; pa1 = a8_1 + ko; pb0 = b8_0 + ko; pb1 = b8_1 + ko;
        } else {
            int ko = (vt - NT_I8) * 64;
            pa0 = af_0 + ko; pa1 = af_1 + ko; pb0 = bf_0 + ko; pb1 = bf_1 + ko;
        }
        __builtin_amdgcn_global_load_lds(
            (const __attribute__((address_space(1))) void*)pa0,
            (__attribute__((address_space(3))) void*)(lds + bufB + dst0), 16, 0, 0);
        __builtin_amdgcn_global_load_lds(
            (const __attribute__((address_space(1))) void*)pa1,
            (__attribute__((address_space(3))) void*)(lds + bufB + dst1), 16, 0, 0);
        __builtin_amdgcn_global_load_lds(
            (const __attribute__((address_space(1))) void*)pb0,
            (__attribute__((address_space(3))) void*)(lds + bufB + 16384 + dst0), 16, 0, 0);
        __builtin_amdgcn_global_load_lds(
            (const __attribute__((address_space(1))) void*)pb1,
            (__attribute__((address_space(3))) void*)(lds + bufB + 16384 + dst1), 16, 0, 0);
    };

    // fragment read byte-offsets (dtype-independent: 64B rows, 16B frags)
    int aOff[8], bOff[4];
#pragma unroll
    for (int mf = 0; mf < 8; ++mf) {
        int ra = wr * 128 + mf * 16 + r16;
        aOff[mf] = ra * 64 + ((((ra >> 1) & 3) ^ kg) << 4);
    }
#pragma unroll
    for (int nf = 0; nf < 4; ++nf) {
        int rb = wc * 64 + nf * 16 + r16;
        bOff[nf] = 16384 + rb * 64 + ((((rb >> 1) & 3) ^ kg) << 4);
    }

    int32x4 acc[8][4];
#pragma unroll
    for (int mf = 0; mf < 8; ++mf)
#pragma unroll
        for (int nf = 0; nf < 4; ++nf)
            acc[mf][nf] = (int32x4){0, 0, 0, 0};

    // prologue: stage tiles 0,1,2; drain tile 0 (vmcnt(8) leaves 1,2 flying)
    stage(0, 0);
    stage(1, 32768);
    stage(2, 65536);
    asm volatile("s_waitcnt vmcnt(8)" ::: "memory");
    __builtin_amdgcn_sched_barrier(0);
    __builtin_amdgcn_s_barrier();
    __builtin_amdgcn_sched_barrier(0);

    // ---- loop 1: 60 i8 K-tiles (exact integer accumulation) ----
    for (int vt = 0; vt < NT_I8; ++vt) {
        const int bufB = (vt & 3) << 15;
        int32x4 bI[4], aI[8];
#pragma unroll
        for (int nf = 0; nf < 4; ++nf)                 // B FIRST
            bI[nf] = *(const int32x4*)(lds + bufB + bOff[nf]);
#pragma unroll
        for (int mf = 0; mf < 8; ++mf)                 // then A
            aI[mf] = *(const int32x4*)(lds + bufB + aOff[mf]);

        stage(vt + 3, ((vt + 3) & 3) << 15);   // vt+3 <= 62 < NT_ALL always

        __builtin_amdgcn_s_setprio(1);
#pragma unroll
        for (int mf = 0; mf < 8; ++mf)                 // consume in arrival order
#pragma unroll
            for (int nf = 0; nf < 4; ++nf)
                acc[mf][nf] = __builtin_amdgcn_mfma_i32_16x16x64_i8(
                    aI[mf], bI[nf], acc[mf][nf], 0, 0, 0);
        __builtin_amdgcn_s_setprio(0);

        asm volatile("s_waitcnt vmcnt(8)" ::: "memory");
        __builtin_amdgcn_sched_barrier(0);
        __builtin_amdgcn_s_barrier();
        __builtin_amdgcn_sched_barrier(0);
    }

    // ---- exact int32 -> f32 conversion (in place, bit-pattern reuse) ----
#pragma unroll
    for (int mf = 0; mf < 8; ++mf)
#pragma unroll
        for (int nf = 0; nf < 4; ++nf) {
            int32x4 vi = acc[mf][nf];
            f32x4 vf;
#pragma unroll
            for (int i = 0; i < 4; ++i) vf[i] = (float)vi[i];
            acc[mf][nf] = __builtin_bit_cast(int32x4, vf);
        }

    // ---- loop 2: 8 bf16 fp sub-tiles (K=32 each) ----
    for (int vt = NT_I8; vt < NT_ALL; ++vt) {
        const int bufB = (vt & 3) << 15;
        short8 bF[4], aF[8];
#pragma unroll
        for (int nf = 0; nf < 4; ++nf)                 // B FIRST
            bF[nf] = *(const short8*)(lds + bufB + bOff[nf]);
#pragma unroll
        for (int mf = 0; mf < 8; ++mf)
            aF[mf] = *(const short8*)(lds + bufB + aOff[mf]);

        if (vt + 3 < NT_ALL)
            stage(vt + 3, ((vt + 3) & 3) << 15);

        __builtin_amdgcn_s_setprio(1);
#pragma unroll
        for (int mf = 0; mf < 8; ++mf)
#pragma unroll
            for (int nf = 0; nf < 4; ++nf)
                acc[mf][nf] = __builtin_bit_cast(int32x4,
                    __builtin_amdgcn_mfma_f32_16x16x32_bf16(
                        aF[mf], bF[nf],
                        __builtin_bit_cast(f32x4, acc[mf][nf]), 0, 0, 0));
        __builtin_amdgcn_s_setprio(0);

        // outstanding stages: u in [vt+1, min(vt+3, 67)]; drain stage(vt+1)
        if (vt <= NT_ALL - 4)
            asm volatile("s_waitcnt vmcnt(8)" ::: "memory");
        else if (vt == NT_ALL - 3)
            asm volatile("s_waitcnt vmcnt(4)" ::: "memory");
        else if (vt == NT_ALL - 2)
            asm volatile("s_waitcnt vmcnt(0)" ::: "memory");
        __builtin_amdgcn_sched_barrier(0);
        __builtin_amdgcn_s_barrier();
        __builtin_amdgcn_sched_barrier(0);
    }

    // epilogue: out = sc*ws*acc + (zero + 8*sc)*reduced + bias
    const int cr4 = kg * 4;
#pragma unroll
    for (int mf = 0; mf < 8; ++mf) {
#pragma unroll
        for (int nf = 0; nf < 4; ++nf) {
            int n = tileN + wc * 64 + nf * 16 + r16;
            float ws = wscale[n];
            float rd = reduced[n];
            float bs = bias[n];
            f32x4 av = __builtin_bit_cast(f32x4, acc[mf][nf]);
#pragma unroll
            for (int i = 0; i < 4; ++i) {
                int m = tileM + wr * 128 + mf * 16 + cr4 + i;
                float sc = scale_ws[m];
                float zr = zero_ws[m];
                out[(size_t)m * OUT_FEAT + n] =
                    sc * ws * av[i]
                    + (zr + sc * 8.0f) * rd + bs;
            }
        }
    }
}

// ------------------------------------------------------------------ launch ---
extern "C" void kernel_launch(void* const* d_in, const int* in_sizes, int n_in,
                              void* d_out, int out_size, void* d_ws, size_t ws_size,
                              hipStream_t stream)
{
    const void* px = 0; const void* pw = 0; const void* pfpw = 0;
    const void* pii = 0; const void* pfi = 0;
    const void* p4096[3] = {0, 0, 0}; int n4096 = 0;
    for (int i = 0; i < n_in; ++i) {
        switch (in_sizes[i]) {
            case 16777216: px = d_in[i]; break;
            case 7864320:  pw = d_in[i]; break;
            case 1048576:  pfpw = d_in[i]; break;
            case 3840:     pii = d_in[i]; break;
            case 256:      pfi = d_in[i]; break;
            case 4096:     if (n4096 < 3) p4096[n4096++] = d_in[i]; break;
            default: break;
        }
    }
    if (!px || !pw || !pfpw || !pii || !pfi || n4096 != 3) return;

    const float* x       = (const float*)px;
    const int*   wpacked = (const int*)pw;
    const float* wscale  = (const float*)p4096[0];
    const float* reduced = (const float*)p4096[1];
    const float* bias    = (const float*)p4096[2];
    const float* fpw     = (const float*)pfpw;
    const int*   int_idx = (const int*)pii;
    const int*   fp_idx  = (const int*)pfi;
    float*       out     = (float*)d_out;

    if (ws_size < (size_t)WS_NEED) return;

    char* ws = (char*)d_ws;
    signed char*    Aq8 = (signed char*)(ws + AQ8_OFF);
    signed char*    Wb8 = (signed char*)(ws + WB8_OFF);
    __hip_bfloat16* Afp = (__hip_bfloat16*)(ws + AFP_OFF);
    __hip_bfloat16* Wfp = (__hip_bfloat16*)(ws + WFP_OFF);
    float* scale_ws     = (float*)(ws + SCALE_OFF);
    float* zero_ws      = (float*)(ws + ZERO_OFF);

    prep_kernel<<<TOKENS + OUT_FEAT, 256, 0, stream>>>(
        x, int_idx, fp_idx, wpacked, fpw, wscale,
        Aq8, Afp, Wb8, Wfp, scale_ws, zero_ws);
    gemm256_i8<<<256, 512, 0, stream>>>(Aq8, Afp, Wb8, Wfp,
                                        scale_ws, zero_ws,
                                        wscale, reduced, bias, out);
}